// Round 2
// baseline (970.177 us; speedup 1.0000x reference)
//
#include <hip/hip_runtime.h>
#include <hip/hip_bf16.h>
#include <stdint.h>

#define N_NODES 100000

typedef unsigned short us16;

__device__ __forceinline__ float us2f(us16 u){
  union{ unsigned int i; float f; } x; x.i = ((unsigned int)u) << 16; return x.f;
}
__device__ __forceinline__ us16 f2us(float f){
  union{ float f; unsigned int i; } x; x.f = f;
  unsigned int i = x.i;
  unsigned int r = (i + 0x7FFFu + ((i >> 16) & 1u)) >> 16;
  return (us16)r;
}

// ---------------- init ----------------
__global__ __launch_bounds__(256) void k_init(float* __restrict__ deg0, float* __restrict__ deg1,
                                              int* __restrict__ cnt, int* __restrict__ fill, int n2){
  int i = blockIdx.x*256 + threadIdx.x;
  if (i < n2){ cnt[i]=0; fill[i]=0; }
  if (i < N_NODES){ deg0[i]=1.0f; deg1[i]=1.0f; }
}

// ---------------- degree + per-(type,dst) counts ----------------
__global__ __launch_bounds__(256) void k_edge_deg(const int* __restrict__ dst,
                                                  const int* __restrict__ et, const float* __restrict__ ew,
                                                  float* __restrict__ deg0, float* __restrict__ deg1,
                                                  int* __restrict__ cnt, int E){
  int e = blockIdx.x*256 + threadIdx.x;
  if (e>=E) return;
  int d = dst[e]; int t = et[e]; float w = ew[e];
  atomicAdd((t==0)?&deg0[d]:&deg1[d], w);
  atomicAdd(&cnt[t*N_NODES + d], 1);
}

__global__ __launch_bounds__(256) void k_dis(const float* __restrict__ deg0, const float* __restrict__ deg1,
                                             float* __restrict__ dis0, float* __restrict__ dis1, int n){
  int i = blockIdx.x*256+threadIdx.x;
  if(i<n){ dis0[i]=rsqrtf(deg0[i]); dis1[i]=rsqrtf(deg1[i]); }
}

// ---------------- exclusive scan over M elements (3 pass) ----------------
__global__ __launch_bounds__(256) void k_scan_reduce(const int* __restrict__ in, int* __restrict__ bsum, int M){
  __shared__ int sd[256];
  int base = blockIdx.x*2048; int t = threadIdx.x;
  int sum = 0;
  #pragma unroll
  for(int i=0;i<8;i++){ int p = base + t*8 + i; if(p<M) sum += in[p]; }
  sd[t]=sum; __syncthreads();
  for(int s=128;s>0;s>>=1){ if(t<s) sd[t]+=sd[t+s]; __syncthreads(); }
  if(t==0) bsum[blockIdx.x]=sd[0];
}
__global__ void k_scan_top(int* __restrict__ bsum, int B){
  if (threadIdx.x==0){ int run=0; for(int i=0;i<B;i++){ int v=bsum[i]; bsum[i]=run; run+=v; } }
}
__global__ __launch_bounds__(256) void k_scan_apply(const int* __restrict__ in, const int* __restrict__ bsum,
                                                    int* __restrict__ out, int M){
  __shared__ int sd[256];
  int base = blockIdx.x*2048; int t = threadIdx.x;
  int loc[8]; int sum=0;
  #pragma unroll
  for(int i=0;i<8;i++){ int p = base + t*8 + i; int v = (p<M)?in[p]:0; loc[i]=sum; sum+=v; }
  sd[t]=sum; __syncthreads();
  for(int ofs=1;ofs<256;ofs<<=1){
    int v = (t>=ofs)? sd[t-ofs] : 0;
    __syncthreads();
    sd[t]+=v;
    __syncthreads();
  }
  int excl = ((t==0)?0:sd[t-1]) + bsum[blockIdx.x];
  #pragma unroll
  for(int i=0;i<8;i++){ int p = base + t*8 + i; if(p<M) out[p]=excl+loc[i]; }
}

// ---------------- CSR fill ----------------
__global__ __launch_bounds__(256) void k_edge_fill(const int* __restrict__ src, const int* __restrict__ dst,
  const int* __restrict__ et, const float* __restrict__ ew,
  const float* __restrict__ dis0, const float* __restrict__ dis1,
  const int* __restrict__ rp, int* __restrict__ fill,
  int* __restrict__ csr_src, float* __restrict__ csr_coef, int E){
  int e = blockIdx.x*256+threadIdx.x;
  if(e>=E) return;
  int s=src[e], d=dst[e], t=et[e]; float w=ew[e];
  const float* dis = (t==0)?dis0:dis1;
  float c = dis[s]*w*dis[d];
  int idx = t*N_NODES + d;
  int pos = rp[idx] + atomicAdd(&fill[idx],1);
  csr_src[pos]=s; csr_coef[pos]=c;
}

// ---------- tiled GEMM: C[n,MC](bf16) = A[n,KC]@W[KC,MC] (+bias/addv, relu) ----------
// A is bf16 (AT=us16) or f32 (AT=float). K>128 reads A1 for columns >=128.
template<int MC, typename AT>
__global__ __launch_bounds__(256) void k_gemm(const AT* __restrict__ A0, const AT* __restrict__ A1, int lda,
                                              const float* __restrict__ W,
                                              const float* __restrict__ bias,
                                              const float* __restrict__ addv,
                                              us16* __restrict__ C, int ldc,
                                              int n, int KC, int relu){
  constexpr int CPT = MC/16;   // cols per thread (8 or 4)
  __shared__ float As[64][68];
  __shared__ float Ws[64][MC];
  const int tid = threadIdx.x;
  const int cg = tid & 15, rg = tid >> 4;
  const int rowBase = blockIdx.x*64;
  float acc[4][CPT];
  #pragma unroll
  for(int i=0;i<4;i++)
    #pragma unroll
    for(int j=0;j<CPT;j++) acc[i][j]=0.f;

  for(int kk=0; kk<KC; kk+=64){
    const AT* A = (kk < 128) ? A0 : A1;
    int kcol = (kk < 128) ? kk : (kk - 128);
    // stage A tile: 64 rows x 64 cols, each thread 2 chunks of 8 elements
    #pragma unroll
    for(int h=0;h<2;h++){
      int idx = h*256 + tid;        // 0..511
      int r  = idx >> 3;
      int c8 = (idx & 7) * 8;
      int row = rowBase + r;
      float v[8];
      if(row < n){
        if constexpr (sizeof(AT)==2){
          uint4 u = *(const uint4*)(A + (size_t)row*lda + kcol + c8);
          const us16* p = (const us16*)&u;
          #pragma unroll
          for(int j=0;j<8;j++) v[j] = us2f(p[j]);
        } else {
          float4 f0 = *(const float4*)(A + (size_t)row*lda + kcol + c8);
          float4 f1 = *(const float4*)(A + (size_t)row*lda + kcol + c8 + 4);
          v[0]=f0.x; v[1]=f0.y; v[2]=f0.z; v[3]=f0.w;
          v[4]=f1.x; v[5]=f1.y; v[6]=f1.z; v[7]=f1.w;
        }
      } else {
        #pragma unroll
        for(int j=0;j<8;j++) v[j]=0.f;
      }
      *(float4*)&As[r][c8]   = make_float4(v[0],v[1],v[2],v[3]);
      *(float4*)&As[r][c8+4] = make_float4(v[4],v[5],v[6],v[7]);
    }
    // stage W tile (f32)
    constexpr int WF4 = 64*MC/4;
    #pragma unroll
    for(int p=0;p<WF4/256;p++){
      int idx = p*256 + tid;
      int kr = idx/(MC/4);
      int c4 = idx%(MC/4);
      *(float4*)&Ws[kr][c4*4] = *(const float4*)(W + (size_t)(kk+kr)*MC + c4*4);
    }
    __syncthreads();
    #pragma unroll 2
    for(int k=0;k<64;k++){
      float a[4];
      #pragma unroll
      for(int i=0;i<4;i++) a[i]=As[rg*4+i][k];
      if constexpr (MC==128){
        float4 w0=*(const float4*)&Ws[k][cg*8];
        float4 w1=*(const float4*)&Ws[k][cg*8+4];
        #pragma unroll
        for(int i=0;i<4;i++){
          acc[i][0]+=a[i]*w0.x; acc[i][1]+=a[i]*w0.y; acc[i][2]+=a[i]*w0.z; acc[i][3]+=a[i]*w0.w;
          acc[i][4]+=a[i]*w1.x; acc[i][5]+=a[i]*w1.y; acc[i][6]+=a[i]*w1.z; acc[i][7]+=a[i]*w1.w;
        }
      } else {
        float4 w0=*(const float4*)&Ws[k][cg*4];
        #pragma unroll
        for(int i=0;i<4;i++){
          acc[i][0]+=a[i]*w0.x; acc[i][1]+=a[i]*w0.y; acc[i][2]+=a[i]*w0.z; acc[i][3]+=a[i]*w0.w;
        }
      }
    }
    __syncthreads();
  }
  float badd[CPT];
  #pragma unroll
  for(int j=0;j<CPT;j++){
    int c = cg*CPT + j;
    float b = 0.f;
    if(bias) b += bias[c];
    if(addv) b += addv[c];
    badd[j]=b;
  }
  #pragma unroll
  for(int i=0;i<4;i++){
    int row = rowBase + rg*4 + i;
    if(row>=n) continue;
    us16 ob[CPT];
    #pragma unroll
    for(int j=0;j<CPT;j++){
      float v = acc[i][j]+badd[j];
      if(relu) v = fmaxf(v,0.f);
      ob[j] = f2us(v);
    }
    if constexpr (CPT==8){
      *(uint4*)(C + (size_t)row*ldc + cg*8) = *(uint4*)ob;
    } else {
      *(uint2*)(C + (size_t)row*ldc + cg*4) = *(uint2*)ob;
    }
  }
}

// ------------- aggregation + self-loop + bias + BN + (relu | residual) -------------
// lane owns cols {2*lane, 2*lane+1}; T/out/resid are bf16 [*,128]
__global__ __launch_bounds__(256) void k_agg(const us16* __restrict__ T,
  const int* __restrict__ csr_src, const float* __restrict__ csr_coef,
  const int* __restrict__ rp, const int* __restrict__ cnt, int rowOfs,
  const float* __restrict__ dis,
  const float* __restrict__ bias, const float* __restrict__ gamma, const float* __restrict__ beta,
  const float* __restrict__ rm, const float* __restrict__ rv,
  const us16* __restrict__ resid,
  us16* __restrict__ out, int relu, int n){
  int wid = threadIdx.x >> 6, lane = threadIdx.x & 63;
  int r = blockIdx.x*4 + wid;
  if (r >= n) return;
  int c0 = lane*2;
  int idx = rowOfs + r;
  int e0 = rp[idx], e1 = e0 + cnt[idx];
  float acc0=0.f, acc1=0.f;
  for(int e=e0;e<e1;e++){
    int s = csr_src[e];
    float c = csr_coef[e];
    unsigned int u = *(const unsigned int*)(T + (size_t)s*128 + c0);
    acc0 += c*us2f((us16)(u & 0xffffu));
    acc1 += c*us2f((us16)(u >> 16));
  }
  float d = dis[r]; float invdeg = d*d;
  unsigned int uself = *(const unsigned int*)(T + (size_t)r*128 + c0);
  float o0 = acc0 + us2f((us16)(uself & 0xffffu))*invdeg + bias[c0];
  float o1 = acc1 + us2f((us16)(uself >> 16))*invdeg + bias[c0+1];
  float sc0 = gamma[c0]  * rsqrtf(rv[c0]  + 1e-5f);
  float sc1 = gamma[c0+1]* rsqrtf(rv[c0+1]+ 1e-5f);
  o0 = (o0 - rm[c0])*sc0 + beta[c0];
  o1 = (o1 - rm[c0+1])*sc1 + beta[c0+1];
  if (relu){ o0=fmaxf(o0,0.f); o1=fmaxf(o1,0.f); }
  if (resid){
    unsigned int ur = *(const unsigned int*)(resid + (size_t)r*128 + c0);
    o0 += us2f((us16)(ur & 0xffffu));
    o1 += us2f((us16)(ur >> 16));
  }
  unsigned int up = (unsigned int)f2us(o0) | ((unsigned int)f2us(o1) << 16);
  *(unsigned int*)(out + (size_t)r*128 + c0) = up;
}

// ------------- seed constant: s0@W1[256:384] + s1@W1[384:512] + b1 -------------
__global__ void k_const64(const us16* __restrict__ X0, const us16* __restrict__ X1,
                          const int* __restrict__ seed,
                          const float* __restrict__ pw1, const float* __restrict__ pb1,
                          float* __restrict__ c64){
  int j = threadIdx.x;  // 64 threads
  int s = seed[0];
  const us16* x0 = X0 + (size_t)s*128;
  const us16* x1 = X1 + (size_t)s*128;
  float acc = pb1[j];
  for(int k=0;k<128;k++) acc += us2f(x0[k]) * pw1[(256+k)*64 + j];
  for(int k=0;k<128;k++) acc += us2f(x1[k]) * pw1[(384+k)*64 + j];
  c64[j]=acc;
}

// ------------- final dot: out[r] = Z2[r]·w3 + b3 -------------
__global__ __launch_bounds__(256) void k_outdot(const us16* __restrict__ Z2, const float* __restrict__ w3,
                                                const float* __restrict__ b3, float* __restrict__ out, int n){
  int r = blockIdx.x*256 + threadIdx.x;
  if(r>=n) return;
  const us16* z = Z2 + (size_t)r*64;
  float acc = b3[0];
  #pragma unroll 8
  for(int j=0;j<64;j++) acc += us2f(z[j])*w3[j];
  out[r]=acc;
}

extern "C" void kernel_launch(void* const* d_in, const int* in_sizes, int n_in,
                              void* d_out, int out_size, void* d_ws, size_t ws_size,
                              hipStream_t stream){
  const int N = N_NODES;
  const int E = in_sizes[2];
  const float* x   = (const float*)d_in[0];
  const int*   ei  = (const int*)d_in[1];
  const int*   et  = (const int*)d_in[2];
  const float* ew  = (const float*)d_in[3];
  const int*   seed= (const int*)d_in[4];
  const float* ft_w= (const float*)d_in[5];
  const float* ft_b= (const float*)d_in[6];
  const float* g0_w= (const float*)d_in[7];
  const float* g0_b= (const float*)d_in[8];
  const float* g0_g= (const float*)d_in[9];
  const float* g0_be=(const float*)d_in[10];
  const float* g0_rm=(const float*)d_in[11];
  const float* g0_rv=(const float*)d_in[12];
  const float* g1_w= (const float*)d_in[13];
  const float* g1_b= (const float*)d_in[14];
  const float* g1_g= (const float*)d_in[15];
  const float* g1_be=(const float*)d_in[16];
  const float* g1_rm=(const float*)d_in[17];
  const float* g1_rv=(const float*)d_in[18];
  const float* p_w1= (const float*)d_in[19];
  const float* p_b1= (const float*)d_in[20];
  const float* p_w2= (const float*)d_in[21];
  const float* p_b2= (const float*)d_in[22];
  const float* p_w3= (const float*)d_in[23];
  const float* p_b3= (const float*)d_in[24];
  float* out = (float*)d_out;

  char* wsp = (char*)d_ws;
  auto alloc = [&](size_t bytes)->char*{ char* p = wsp; wsp += (bytes + 255) & ~(size_t)255; return p; };
  // feature buffers (bf16, [N,128] each): total 102.4MB
  us16* B0 = (us16*)alloc((size_t)N*128*2);
  us16* B1 = (us16*)alloc((size_t)N*128*2);
  us16* B2 = (us16*)alloc((size_t)N*128*2);
  us16* B3 = (us16*)alloc((size_t)N*128*2);
  int*   csr_src  = (int*)alloc((size_t)E*4);
  float* csr_coef = (float*)alloc((size_t)E*4);
  float* deg0=(float*)alloc((size_t)N*4);
  float* deg1=(float*)alloc((size_t)N*4);
  float* dis0=(float*)alloc((size_t)N*4);
  float* dis1=(float*)alloc((size_t)N*4);
  int* cnt =(int*)alloc((size_t)2*N*4);
  int* fill=(int*)alloc((size_t)2*N*4);
  int* rp  =(int*)alloc((size_t)2*N*4);
  int* bsum=(int*)alloc(4096);
  float* c64=(float*)alloc(256);
  us16* Z1 = B0;   // reuse: B0 dead by predictor time ([N,64] bf16 fits)
  us16* Z2 = B1;

  const int* srcp = ei;
  const int* dstp = ei + E;

  // ---- graph preprocessing ----
  k_init<<<(2*N+255)/256,256,0,stream>>>(deg0,deg1,cnt,fill,2*N);
  k_edge_deg<<<(E+255)/256,256,0,stream>>>(dstp,et,ew,deg0,deg1,cnt,E);
  k_dis<<<(N+255)/256,256,0,stream>>>(deg0,deg1,dis0,dis1,N);
  int M = 2*N;
  int SB = (M+2047)/2048;
  k_scan_reduce<<<SB,256,0,stream>>>(cnt,bsum,M);
  k_scan_top<<<1,64,0,stream>>>(bsum,SB);
  k_scan_apply<<<SB,256,0,stream>>>(cnt,bsum,rp,M);
  k_edge_fill<<<(E+255)/256,256,0,stream>>>(srcp,dstp,et,ew,dis0,dis1,rp,fill,csr_src,csr_coef,E);

  int GB = (N+63)/64;
  int AB = (N+3)/4;
  // ---- feature transform: B0 = relu(x@ft_w + ft_b) ----
  k_gemm<128,float><<<GB,256,0,stream>>>(x,x,128, ft_w, ft_b, nullptr, B0,128, N,128,1);
  // ---- both blocks' layer-0 linear (frees B0 early) ----
  k_gemm<128,us16><<<GB,256,0,stream>>>(B0,B0,128, g0_w, nullptr,nullptr, B1,128, N,128,0);
  k_gemm<128,us16><<<GB,256,0,stream>>>(B0,B0,128, g1_w, nullptr,nullptr, B2,128, N,128,0);
  // ---- block 0 ----
  k_agg<<<AB,256,0,stream>>>(B1,csr_src,csr_coef,rp,cnt,0,dis0,
                             g0_b,g0_g,g0_be,g0_rm,g0_rv, nullptr, B0,1,N);      // h0 -> B0
  k_gemm<128,us16><<<GB,256,0,stream>>>(B0,B0,128, g0_w+16384, nullptr,nullptr, B1,128, N,128,0);
  k_agg<<<AB,256,0,stream>>>(B1,csr_src,csr_coef,rp,cnt,0,dis0,
                             g0_b+128,g0_g+128,g0_be+128,g0_rm+128,g0_rv+128, B0, B3,0,N); // x0 -> B3
  // ---- block 1 ----
  k_agg<<<AB,256,0,stream>>>(B2,csr_src,csr_coef,rp,cnt,N,dis1,
                             g1_b,g1_g,g1_be,g1_rm,g1_rv, nullptr, B0,1,N);      // h1 -> B0
  k_gemm<128,us16><<<GB,256,0,stream>>>(B0,B0,128, g1_w+16384, nullptr,nullptr, B1,128, N,128,0);
  k_agg<<<AB,256,0,stream>>>(B1,csr_src,csr_coef,rp,cnt,N,dis1,
                             g1_b+128,g1_g+128,g1_be+128,g1_rm+128,g1_rv+128, B0, B2,0,N); // x1 -> B2
  // ---- predictor ----
  k_const64<<<1,64,0,stream>>>(B3,B2,seed,p_w1,p_b1,c64);
  k_gemm<64,us16><<<GB,256,0,stream>>>(B3,B2,128, p_w1, nullptr, c64, Z1,64, N,256,1);
  k_gemm<64,us16><<<GB,256,0,stream>>>(Z1,Z1,64,  p_w2, p_b2, nullptr, Z2,64, N,64,1);
  k_outdot<<<(N+255)/256,256,0,stream>>>(Z2,p_w3,p_b3,out,N);
}

// Round 6
// 776.198 us; speedup vs baseline: 1.2499x; 1.2499x over previous
//
#include <hip/hip_runtime.h>
#include <hip/hip_bf16.h>
#include <stdint.h>

#define N_NODES 100000

typedef unsigned short us16;
typedef short bf16x8 __attribute__((ext_vector_type(8)));
typedef float f32x4 __attribute__((ext_vector_type(4)));

__device__ __forceinline__ float us2f(us16 u){
  union{ unsigned int i; float f; } x; x.i = ((unsigned int)u) << 16; return x.f;
}
__device__ __forceinline__ us16 f2us(float f){
  union{ float f; unsigned int i; } x; x.f = f;
  unsigned int i = x.i;
  unsigned int r = (i + 0x7FFFu + ((i >> 16) & 1u)) >> 16;
  return (us16)r;
}

// ---------------- init (R1-exact) ----------------
__global__ __launch_bounds__(256) void k_init(float* __restrict__ deg0, float* __restrict__ deg1,
                                              int* __restrict__ cnt, int* __restrict__ fill, int n2){
  int i = blockIdx.x*256 + threadIdx.x;
  if (i < n2){ cnt[i]=0; fill[i]=0; }
  if (i < N_NODES){ deg0[i]=1.0f; deg1[i]=1.0f; }
}

// ---------------- degree + per-(type,dst) counts (R1-exact) ----------------
__global__ __launch_bounds__(256) void k_edge_deg(const int* __restrict__ dst,
                                                  const int* __restrict__ et, const float* __restrict__ ew,
                                                  float* __restrict__ deg0, float* __restrict__ deg1,
                                                  int* __restrict__ cnt, int E){
  int e = blockIdx.x*256 + threadIdx.x;
  if (e>=E) return;
  int d = dst[e]; int t = et[e]; float w = ew[e];
  atomicAdd((t==0)?&deg0[d]:&deg1[d], w);
  atomicAdd(&cnt[t*N_NODES + d], 1);
}

__global__ __launch_bounds__(256) void k_dis(const float* __restrict__ deg0, const float* __restrict__ deg1,
                                             float* __restrict__ dis0, float* __restrict__ dis1, int n){
  int i = blockIdx.x*256+threadIdx.x;
  if(i<n){ dis0[i]=rsqrtf(deg0[i]); dis1[i]=rsqrtf(deg1[i]); }
}

// ---------------- exclusive scan over M elements (R1-exact) ----------------
__global__ __launch_bounds__(256) void k_scan_reduce(const int* __restrict__ in, int* __restrict__ bsum, int M){
  __shared__ int sd[256];
  int base = blockIdx.x*2048; int t = threadIdx.x;
  int sum = 0;
  #pragma unroll
  for(int i=0;i<8;i++){ int p = base + t*8 + i; if(p<M) sum += in[p]; }
  sd[t]=sum; __syncthreads();
  for(int s=128;s>0;s>>=1){ if(t<s) sd[t]+=sd[t+s]; __syncthreads(); }
  if(t==0) bsum[blockIdx.x]=sd[0];
}
__global__ void k_scan_top(int* __restrict__ bsum, int B){
  if (threadIdx.x==0){ int run=0; for(int i=0;i<B;i++){ int v=bsum[i]; bsum[i]=run; run+=v; } }
}
__global__ __launch_bounds__(256) void k_scan_apply(const int* __restrict__ in, const int* __restrict__ bsum,
                                                    int* __restrict__ out, int M){
  __shared__ int sd[256];
  int base = blockIdx.x*2048; int t = threadIdx.x;
  int loc[8]; int sum=0;
  #pragma unroll
  for(int i=0;i<8;i++){ int p = base + t*8 + i; int v = (p<M)?in[p]:0; loc[i]=sum; sum+=v; }
  sd[t]=sum; __syncthreads();
  for(int ofs=1;ofs<256;ofs<<=1){
    int v = (t>=ofs)? sd[t-ofs] : 0;
    __syncthreads();
    sd[t]+=v;
    __syncthreads();
  }
  int excl = ((t==0)?0:sd[t-1]) + bsum[blockIdx.x];
  #pragma unroll
  for(int i=0;i<8;i++){ int p = base + t*8 + i; if(p<M) out[p]=excl+loc[i]; }
}

// ---------------- CSR fill (R1-exact) ----------------
__global__ __launch_bounds__(256) void k_edge_fill(const int* __restrict__ src, const int* __restrict__ dst,
  const int* __restrict__ et, const float* __restrict__ ew,
  const float* __restrict__ dis0, const float* __restrict__ dis1,
  const int* __restrict__ rp, int* __restrict__ fill,
  int* __restrict__ csr_src, float* __restrict__ csr_coef, int E){
  int e = blockIdx.x*256+threadIdx.x;
  if(e>=E) return;
  int s=src[e], d=dst[e], t=et[e]; float w=ew[e];
  const float* dis = (t==0)?dis0:dis1;
  float c = dis[s]*w*dis[d];
  int idx = t*N_NODES + d;
  int pos = rp[idx] + atomicAdd(&fill[idx],1);
  csr_src[pos]=s; csr_coef[pos]=c;
}

// ---------------- f32 -> bf16 convert (x) ----------------
__global__ __launch_bounds__(256) void k_cvt(const float* __restrict__ x, us16* __restrict__ o, int total8){
  int i = blockIdx.x*256+threadIdx.x;
  if(i>=total8) return;
  const float4* p = (const float4*)(x + (size_t)i*8);
  float4 a=p[0], b=p[1];
  us16 ob[8] = {f2us(a.x),f2us(a.y),f2us(a.z),f2us(a.w),f2us(b.x),f2us(b.y),f2us(b.z),f2us(b.w)};
  *(uint4*)(o + (size_t)i*8) = *(uint4*)ob;
}

// ---------------- weight prep: f32 [K][NC] -> bf16 transposed [NC][K] ----------------
__global__ __launch_bounds__(256) void k_prepw(const float* __restrict__ ft_w,
                                               const float* __restrict__ g0_w, const float* __restrict__ g1_w,
                                               const float* __restrict__ p_w1, const float* __restrict__ p_w2,
                                               us16* __restrict__ wt){
  int m = blockIdx.y;
  const float* srcp; int K, NCc; us16* dstp;
  switch(m){
    case 0: srcp=ft_w;        K=128; NCc=128; dstp=wt;        break;
    case 1: srcp=g0_w;        K=128; NCc=128; dstp=wt+16384;  break;
    case 2: srcp=g0_w+16384;  K=128; NCc=128; dstp=wt+32768;  break;
    case 3: srcp=g1_w;        K=128; NCc=128; dstp=wt+49152;  break;
    case 4: srcp=g1_w+16384;  K=128; NCc=128; dstp=wt+65536;  break;
    case 5: srcp=p_w1;        K=256; NCc=64;  dstp=wt+81920;  break;
    default:srcp=p_w2;        K=64;  NCc=64;  dstp=wt+98304;  break;
  }
  int idx = blockIdx.x*256+threadIdx.x;
  if(idx >= K*NCc) return;
  int nn = idx / K, k = idx - nn*K;
  dstp[idx] = f2us(srcp[(size_t)k*NCc + nn]);
}

// ---------- MFMA GEMM: C[n,NC](bf16) = A[n,KC](bf16) @ W[KC,NC] (+bias/addv, relu) ----------
// Wt is pre-transposed bf16 [NC][KC]. A splits at k=128 (A0 then A1). BM=128, 4 waves x 32 rows.
template<int NC>
__global__ __launch_bounds__(256) void k_mgemm(const us16* __restrict__ A0, const us16* __restrict__ A1,
                 int lda, const us16* __restrict__ Wt,
                 const float* __restrict__ bias, const float* __restrict__ addv,
                 us16* __restrict__ C, int ldc, int n, int KC, int relu){
  constexpr int NB = NC/16;
  __shared__ us16 Alds[128*64];
  __shared__ us16 Wlds[NC*64];
  const int tid = threadIdx.x;
  const int lane = tid & 63, wid = tid >> 6;
  const int rowBase = blockIdx.x*128;
  f32x4 zero = {0.f,0.f,0.f,0.f};
  f32x4 acc[2][NB];
  #pragma unroll
  for(int m=0;m<2;m++)
    #pragma unroll
    for(int nb=0;nb<NB;nb++) acc[m][nb] = zero;

  for(int kk=0; kk<KC; kk+=64){
    const us16* Ab = (kk<128)? A0 : A1;
    const int kc = (kk<128)? kk : (kk-128);
    // stage A tile 128 rows x 64 k, XOR-swizzled 16B units: unit u of row r stored at u^(r&7)
    #pragma unroll
    for(int p=0;p<4;p++){
      int idx = p*256 + tid;
      int r = idx>>3, u = idx&7;
      int row = rowBase + r;
      uint4 v = make_uint4(0u,0u,0u,0u);
      if(row<n) v = *(const uint4*)(Ab + (size_t)row*lda + kc + u*8);
      *(uint4*)&Alds[(r*8 + (u ^ (r&7)))*8] = v;
    }
    // stage Wt tile NC cols x 64 k, same swizzle
    #pragma unroll
    for(int p=0;p<NB/2;p++){
      int idx = p*256 + tid;
      int cI = idx>>3, u = idx&7;
      uint4 v = *(const uint4*)(Wt + (size_t)cI*KC + kk + u*8);
      *(uint4*)&Wlds[(cI*8 + (u ^ (cI&7)))*8] = v;
    }
    __syncthreads();
    #pragma unroll
    for(int ks=0;ks<2;ks++){
      bf16x8 af[2];
      #pragma unroll
      for(int m=0;m<2;m++){
        int r = wid*32 + m*16 + (lane&15);
        int u = (ks*4 + (lane>>4)) ^ (r&7);
        af[m] = *(const bf16x8*)&Alds[(r*8+u)*8];
      }
      #pragma unroll
      for(int nb=0;nb<NB;nb++){
        int c2 = nb*16 + (lane&15);
        int u = (ks*4 + (lane>>4)) ^ (c2&7);
        bf16x8 bfv = *(const bf16x8*)&Wlds[(c2*8+u)*8];
        #pragma unroll
        for(int m=0;m<2;m++)
          acc[m][nb] = __builtin_amdgcn_mfma_f32_16x16x32_bf16(af[m], bfv, acc[m][nb], 0,0,0);
      }
    }
    __syncthreads();
  }
  // epilogue: C/D layout col=lane&15, row=(lane>>4)*4+j  [m89-verified]
  #pragma unroll
  for(int nb=0;nb<NB;nb++){
    int col = nb*16 + (lane&15);
    float badd = (bias? bias[col]:0.f) + (addv? addv[col]:0.f);
    #pragma unroll
    for(int m=0;m<2;m++){
      #pragma unroll
      for(int j=0;j<4;j++){
        int row = rowBase + wid*32 + m*16 + (lane>>4)*4 + j;
        if(row<n){
          float v = acc[m][nb][j] + badd;
          if(relu) v = fmaxf(v,0.f);
          C[(size_t)row*ldc + col] = f2us(v);
        }
      }
    }
  }
}

// ------------- aggregation + self-loop + bias + BN + (relu | residual) (R1-exact) -------------
__global__ __launch_bounds__(256) void k_agg(const us16* __restrict__ T,
  const int* __restrict__ csr_src, const float* __restrict__ csr_coef,
  const int* __restrict__ rp, const int* __restrict__ cnt, int rowOfs,
  const float* __restrict__ dis,
  const float* __restrict__ bias, const float* __restrict__ gamma, const float* __restrict__ beta,
  const float* __restrict__ rm, const float* __restrict__ rv,
  const us16* __restrict__ resid,
  us16* __restrict__ out, int relu, int n){
  int wid = threadIdx.x >> 6, lane = threadIdx.x & 63;
  int r = blockIdx.x*4 + wid;
  if (r >= n) return;
  int c0 = lane*2;
  int idx = rowOfs + r;
  int e0 = rp[idx], e1 = e0 + cnt[idx];
  float acc0=0.f, acc1=0.f;
  for(int e=e0;e<e1;e++){
    int s = csr_src[e];
    float c = csr_coef[e];
    unsigned int u = *(const unsigned int*)(T + (size_t)s*128 + c0);
    acc0 += c*us2f((us16)(u & 0xffffu));
    acc1 += c*us2f((us16)(u >> 16));
  }
  float d = dis[r]; float invdeg = d*d;
  unsigned int uself = *(const unsigned int*)(T + (size_t)r*128 + c0);
  float o0 = acc0 + us2f((us16)(uself & 0xffffu))*invdeg + bias[c0];
  float o1 = acc1 + us2f((us16)(uself >> 16))*invdeg + bias[c0+1];
  float sc0 = gamma[c0]  * rsqrtf(rv[c0]  + 1e-5f);
  float sc1 = gamma[c0+1]* rsqrtf(rv[c0+1]+ 1e-5f);
  o0 = (o0 - rm[c0])*sc0 + beta[c0];
  o1 = (o1 - rm[c0+1])*sc1 + beta[c0+1];
  if (relu){ o0=fmaxf(o0,0.f); o1=fmaxf(o1,0.f); }
  if (resid){
    unsigned int ur = *(const unsigned int*)(resid + (size_t)r*128 + c0);
    o0 += us2f((us16)(ur & 0xffffu));
    o1 += us2f((us16)(ur >> 16));
  }
  unsigned int up = (unsigned int)f2us(o0) | ((unsigned int)f2us(o1) << 16);
  *(unsigned int*)(out + (size_t)r*128 + c0) = up;
}

// ------------- seed constant (R1-exact) -------------
__global__ void k_const64(const us16* __restrict__ X0, const us16* __restrict__ X1,
                          const int* __restrict__ seed,
                          const float* __restrict__ pw1, const float* __restrict__ pb1,
                          float* __restrict__ c64){
  int j = threadIdx.x;  // 64 threads
  int s = seed[0];
  const us16* x0 = X0 + (size_t)s*128;
  const us16* x1 = X1 + (size_t)s*128;
  float acc = pb1[j];
  for(int k=0;k<128;k++) acc += us2f(x0[k]) * pw1[(256+k)*64 + j];
  for(int k=0;k<128;k++) acc += us2f(x1[k]) * pw1[(384+k)*64 + j];
  c64[j]=acc;
}

// ------------- final dot (R1-exact) -------------
__global__ __launch_bounds__(256) void k_outdot(const us16* __restrict__ Z2, const float* __restrict__ w3,
                                                const float* __restrict__ b3, float* __restrict__ out, int n){
  int r = blockIdx.x*256 + threadIdx.x;
  if(r>=n) return;
  const us16* z = Z2 + (size_t)r*64;
  float acc = b3[0];
  #pragma unroll 8
  for(int j=0;j<64;j++) acc += us2f(z[j])*w3[j];
  out[r]=acc;
}

extern "C" void kernel_launch(void* const* d_in, const int* in_sizes, int n_in,
                              void* d_out, int out_size, void* d_ws, size_t ws_size,
                              hipStream_t stream){
  const int N = N_NODES;
  const int E = in_sizes[2];
  const float* x   = (const float*)d_in[0];
  const int*   ei  = (const int*)d_in[1];
  const int*   et  = (const int*)d_in[2];
  const float* ew  = (const float*)d_in[3];
  const int*   seed= (const int*)d_in[4];
  const float* ft_w= (const float*)d_in[5];
  const float* ft_b= (const float*)d_in[6];
  const float* g0_w= (const float*)d_in[7];
  const float* g0_b= (const float*)d_in[8];
  const float* g0_g= (const float*)d_in[9];
  const float* g0_be=(const float*)d_in[10];
  const float* g0_rm=(const float*)d_in[11];
  const float* g0_rv=(const float*)d_in[12];
  const float* g1_w= (const float*)d_in[13];
  const float* g1_b= (const float*)d_in[14];
  const float* g1_g= (const float*)d_in[15];
  const float* g1_be=(const float*)d_in[16];
  const float* g1_rm=(const float*)d_in[17];
  const float* g1_rv=(const float*)d_in[18];
  const float* p_w1= (const float*)d_in[19];
  const float* p_b1= (const float*)d_in[20];
  const float* p_w2= (const float*)d_in[21];
  const float* p_b2= (const float*)d_in[22];
  const float* p_w3= (const float*)d_in[23];
  const float* p_b3= (const float*)d_in[24];
  float* out = (float*)d_out;

  // R1-exact allocation order & footprint (119,204,352 B, proven passing).
  char* wsp = (char*)d_ws;
  auto alloc = [&](size_t bytes)->char*{ char* p = wsp; wsp += (bytes + 255) & ~(size_t)255; return p; };
  us16* B0 = (us16*)alloc((size_t)N*128*2);
  us16* B1 = (us16*)alloc((size_t)N*128*2);
  us16* B2 = (us16*)alloc((size_t)N*128*2);
  us16* B3 = (us16*)alloc((size_t)N*128*2);
  int*   csr_src  = (int*)alloc((size_t)E*4);
  float* csr_coef = (float*)alloc((size_t)E*4);
  float* deg0=(float*)alloc((size_t)N*4);
  float* deg1=(float*)alloc((size_t)N*4);
  float* dis0=(float*)alloc((size_t)N*4);
  float* dis1=(float*)alloc((size_t)N*4);
  int* cnt =(int*)alloc((size_t)2*N*4);
  int* fill=(int*)alloc((size_t)2*N*4);
  int* rp  =(int*)alloc((size_t)2*N*4);
  int* bsum=(int*)alloc(4096);
  float* c64=(float*)alloc(256);
  // bf16 weights alias deg0/deg1 (800,000 B >= 204,800 B; deg dead after k_dis,
  // k_prepw launches after k_dis on the same stream).
  us16* wt = (us16*)deg0;
  us16* Z1 = B0;
  us16* Z2 = B1;

  const int* srcp = ei;
  const int* dstp = ei + E;

  // ---- graph preprocessing (R1-exact) ----
  k_init<<<(2*N+255)/256,256,0,stream>>>(deg0,deg1,cnt,fill,2*N);
  k_edge_deg<<<(E+255)/256,256,0,stream>>>(dstp,et,ew,deg0,deg1,cnt,E);
  k_dis<<<(N+255)/256,256,0,stream>>>(deg0,deg1,dis0,dis1,N);
  int M = 2*N;
  int SB = (M+2047)/2048;
  k_scan_reduce<<<SB,256,0,stream>>>(cnt,bsum,M);
  k_scan_top<<<1,64,0,stream>>>(bsum,SB);
  k_scan_apply<<<SB,256,0,stream>>>(cnt,bsum,rp,M);
  k_edge_fill<<<(E+255)/256,256,0,stream>>>(srcp,dstp,et,ew,dis0,dis1,rp,fill,csr_src,csr_coef,E);

  // ---- weight prep (after k_dis: deg0/deg1 dead) + x conversion ----
  dim3 pg(64,7);
  k_prepw<<<pg,256,0,stream>>>(ft_w,g0_w,g1_w,p_w1,p_w2,wt);
  k_cvt<<<(N*16+255)/256,256,0,stream>>>(x, B3, N*16);

  const us16* wt_ft = wt;
  const us16* wt_g00= wt+16384;
  const us16* wt_g01= wt+32768;
  const us16* wt_g10= wt+49152;
  const us16* wt_g11= wt+65536;
  const us16* wt_p1 = wt+81920;
  const us16* wt_p2 = wt+98304;

  int GB = (N+127)/128;
  int AB = (N+3)/4;
  // ---- feature transform: B0 = relu(xb@ft_w + ft_b), xb in B3 ----
  k_mgemm<128><<<GB,256,0,stream>>>(B3,B3,128, wt_ft, ft_b, nullptr, B0,128, N,128,1);
  // ---- both blocks' layer-0 linear ----
  k_mgemm<128><<<GB,256,0,stream>>>(B0,B0,128, wt_g00, nullptr,nullptr, B1,128, N,128,0);
  k_mgemm<128><<<GB,256,0,stream>>>(B0,B0,128, wt_g10, nullptr,nullptr, B2,128, N,128,0);
  // ---- block 0 ----
  k_agg<<<AB,256,0,stream>>>(B1,csr_src,csr_coef,rp,cnt,0,dis0,
                             g0_b,g0_g,g0_be,g0_rm,g0_rv, nullptr, B0,1,N);      // h0 -> B0
  k_mgemm<128><<<GB,256,0,stream>>>(B0,B0,128, wt_g01, nullptr,nullptr, B1,128, N,128,0);
  k_agg<<<AB,256,0,stream>>>(B1,csr_src,csr_coef,rp,cnt,0,dis0,
                             g0_b+128,g0_g+128,g0_be+128,g0_rm+128,g0_rv+128, B0, B3,0,N); // x0 -> B3
  // ---- block 1 ----
  k_agg<<<AB,256,0,stream>>>(B2,csr_src,csr_coef,rp,cnt,N,dis1,
                             g1_b,g1_g,g1_be,g1_rm,g1_rv, nullptr, B0,1,N);      // h1 -> B0
  k_mgemm<128><<<GB,256,0,stream>>>(B0,B0,128, wt_g11, nullptr,nullptr, B1,128, N,128,0);
  k_agg<<<AB,256,0,stream>>>(B1,csr_src,csr_coef,rp,cnt,N,dis1,
                             g1_b+128,g1_g+128,g1_be+128,g1_rm+128,g1_rv+128, B0, B2,0,N); // x1 -> B2
  // ---- predictor ----
  k_const64<<<1,64,0,stream>>>(B3,B2,seed,p_w1,p_b1,c64);
  k_mgemm<64><<<GB,256,0,stream>>>(B3,B2,128, wt_p1, nullptr, c64, Z1,64, N,256,1);
  k_mgemm<64><<<GB,256,0,stream>>>(Z1,Z1,64,  wt_p2, p_b2, nullptr, Z2,64, N,64,1);
  k_outdot<<<(N+255)/256,256,0,stream>>>(Z2,p_w3,p_b3,out,N);
}

// Round 7
// 737.871 us; speedup vs baseline: 1.3148x; 1.0519x over previous
//
#include <hip/hip_runtime.h>
#include <hip/hip_bf16.h>
#include <stdint.h>

#define N_NODES 100000

typedef unsigned short us16;
typedef short bf16x8 __attribute__((ext_vector_type(8)));
typedef float f32x4 __attribute__((ext_vector_type(4)));

__device__ __forceinline__ float us2f(us16 u){
  union{ unsigned int i; float f; } x; x.i = ((unsigned int)u) << 16; return x.f;
}
__device__ __forceinline__ us16 f2us(float f){
  union{ float f; unsigned int i; } x; x.f = f;
  unsigned int i = x.i;
  unsigned int r = (i + 0x7FFFu + ((i >> 16) & 1u)) >> 16;
  return (us16)r;
}

// ---------------- init: zero cnt/fill ----------------
__global__ __launch_bounds__(256) void k_init(int* __restrict__ cnt, int* __restrict__ fill, int n2){
  int i = blockIdx.x*256 + threadIdx.x;
  if (i < n2){ cnt[i]=0; fill[i]=0; }
}

// ---------------- per-(type,dst) counts: ONE int atomic per edge ----------------
__global__ __launch_bounds__(256) void k_cnt(const int* __restrict__ dst,
                                             const int* __restrict__ et,
                                             int* __restrict__ cnt, int E){
  int e = blockIdx.x*256 + threadIdx.x;
  if (e>=E) return;
  int d = dst[e]; int t = et[e];
  atomicAdd(&cnt[t*N_NODES + d], 1);
}

// ---------------- exclusive scan over M elements (R1-exact) ----------------
__global__ __launch_bounds__(256) void k_scan_reduce(const int* __restrict__ in, int* __restrict__ bsum, int M){
  __shared__ int sd[256];
  int base = blockIdx.x*2048; int t = threadIdx.x;
  int sum = 0;
  #pragma unroll
  for(int i=0;i<8;i++){ int p = base + t*8 + i; if(p<M) sum += in[p]; }
  sd[t]=sum; __syncthreads();
  for(int s=128;s>0;s>>=1){ if(t<s) sd[t]+=sd[t+s]; __syncthreads(); }
  if(t==0) bsum[blockIdx.x]=sd[0];
}
__global__ void k_scan_top(int* __restrict__ bsum, int B){
  if (threadIdx.x==0){ int run=0; for(int i=0;i<B;i++){ int v=bsum[i]; bsum[i]=run; run+=v; } }
}
__global__ __launch_bounds__(256) void k_scan_apply(const int* __restrict__ in, const int* __restrict__ bsum,
                                                    int* __restrict__ out, int M){
  __shared__ int sd[256];
  int base = blockIdx.x*2048; int t = threadIdx.x;
  int loc[8]; int sum=0;
  #pragma unroll
  for(int i=0;i<8;i++){ int p = base + t*8 + i; int v = (p<M)?in[p]:0; loc[i]=sum; sum+=v; }
  sd[t]=sum; __syncthreads();
  for(int ofs=1;ofs<256;ofs<<=1){
    int v = (t>=ofs)? sd[t-ofs] : 0;
    __syncthreads();
    sd[t]+=v;
    __syncthreads();
  }
  int excl = ((t==0)?0:sd[t-1]) + bsum[blockIdx.x];
  #pragma unroll
  for(int i=0;i<8;i++){ int p = base + t*8 + i; if(p<M) out[p]=excl+loc[i]; }
}

// ---------------- CSR fill (R1-exact mechanics; stores RAW w) ----------------
__global__ __launch_bounds__(256) void k_edge_fill(const int* __restrict__ src, const int* __restrict__ dst,
  const int* __restrict__ et, const float* __restrict__ ew,
  const int* __restrict__ rp, int* __restrict__ fill,
  int* __restrict__ csr_src, float* __restrict__ csr_coef, int E){
  int e = blockIdx.x*256+threadIdx.x;
  if(e>=E) return;
  int s=src[e], d=dst[e], t=et[e]; float w=ew[e];
  int idx = t*N_NODES + d;
  int pos = rp[idx] + atomicAdd(&fill[idx],1);
  csr_src[pos]=s; csr_coef[pos]=w;
}

// ---------------- degree from CSR (sequential, atomic-free) ----------------
__global__ __launch_bounds__(256) void k_deg_csr(const float* __restrict__ csr_coef,
                                                 const int* __restrict__ rp, const int* __restrict__ cnt,
                                                 float* __restrict__ disA, int M){
  int i = blockIdx.x*256+threadIdx.x;
  if(i>=M) return;
  int e0 = rp[i], c = cnt[i];
  float s = 1.0f;
  for(int e=e0; e<e0+c; e++) s += csr_coef[e];
  disA[i] = rsqrtf(s);
}

// ---------------- fold dis[src] into coefficients: coef = w * dis[s] ----------------
__global__ __launch_bounds__(256) void k_coef(const int* __restrict__ csr_src,
                                              float* __restrict__ csr_coef,
                                              const int* __restrict__ rp,
                                              const float* __restrict__ disA, int E){
  int e = blockIdx.x*256+threadIdx.x;
  if(e>=E) return;
  int rpN = rp[N_NODES];               // boundary: first type-1 entry
  int t = (e >= rpN) ? 1 : 0;
  int s = csr_src[e];
  csr_coef[e] *= disA[t*N_NODES + s];
}

// ---------------- f32 -> bf16 convert (x) ----------------
__global__ __launch_bounds__(256) void k_cvt(const float* __restrict__ x, us16* __restrict__ o, int total8){
  int i = blockIdx.x*256+threadIdx.x;
  if(i>=total8) return;
  const float4* p = (const float4*)(x + (size_t)i*8);
  float4 a=p[0], b=p[1];
  us16 ob[8] = {f2us(a.x),f2us(a.y),f2us(a.z),f2us(a.w),f2us(b.x),f2us(b.y),f2us(b.z),f2us(b.w)};
  *(uint4*)(o + (size_t)i*8) = *(uint4*)ob;
}

// ---------------- weight prep: f32 [K][NC] -> bf16 transposed [NC][K] ----------------
__global__ __launch_bounds__(256) void k_prepw(const float* __restrict__ ft_w,
                                               const float* __restrict__ g0_w, const float* __restrict__ g1_w,
                                               const float* __restrict__ p_w1, const float* __restrict__ p_w2,
                                               us16* __restrict__ wt){
  int m = blockIdx.y;
  const float* srcp; int K, NCc; us16* dstp;
  switch(m){
    case 0: srcp=ft_w;        K=128; NCc=128; dstp=wt;        break;
    case 1: srcp=g0_w;        K=128; NCc=128; dstp=wt+16384;  break;
    case 2: srcp=g0_w+16384;  K=128; NCc=128; dstp=wt+32768;  break;
    case 3: srcp=g1_w;        K=128; NCc=128; dstp=wt+49152;  break;
    case 4: srcp=g1_w+16384;  K=128; NCc=128; dstp=wt+65536;  break;
    case 5: srcp=p_w1;        K=256; NCc=64;  dstp=wt+81920;  break;
    default:srcp=p_w2;        K=64;  NCc=64;  dstp=wt+98304;  break;
  }
  int idx = blockIdx.x*256+threadIdx.x;
  if(idx >= K*NCc) return;
  int nn = idx / K, k = idx - nn*K;
  dstp[idx] = f2us(srcp[(size_t)k*NCc + nn]);
}

// ---------- MFMA GEMM (R6-exact, verified): C[n,NC](bf16) = A@W (+bias/addv, relu) ----------
template<int NC>
__global__ __launch_bounds__(256) void k_mgemm(const us16* __restrict__ A0, const us16* __restrict__ A1,
                 int lda, const us16* __restrict__ Wt,
                 const float* __restrict__ bias, const float* __restrict__ addv,
                 us16* __restrict__ C, int ldc, int n, int KC, int relu){
  constexpr int NB = NC/16;
  __shared__ us16 Alds[128*64];
  __shared__ us16 Wlds[NC*64];
  const int tid = threadIdx.x;
  const int lane = tid & 63, wid = tid >> 6;
  const int rowBase = blockIdx.x*128;
  f32x4 zero = {0.f,0.f,0.f,0.f};
  f32x4 acc[2][NB];
  #pragma unroll
  for(int m=0;m<2;m++)
    #pragma unroll
    for(int nb=0;nb<NB;nb++) acc[m][nb] = zero;

  for(int kk=0; kk<KC; kk+=64){
    const us16* Ab = (kk<128)? A0 : A1;
    const int kc = (kk<128)? kk : (kk-128);
    #pragma unroll
    for(int p=0;p<4;p++){
      int idx = p*256 + tid;
      int r = idx>>3, u = idx&7;
      int row = rowBase + r;
      uint4 v = make_uint4(0u,0u,0u,0u);
      if(row<n) v = *(const uint4*)(Ab + (size_t)row*lda + kc + u*8);
      *(uint4*)&Alds[(r*8 + (u ^ (r&7)))*8] = v;
    }
    #pragma unroll
    for(int p=0;p<NB/2;p++){
      int idx = p*256 + tid;
      int cI = idx>>3, u = idx&7;
      uint4 v = *(const uint4*)(Wt + (size_t)cI*KC + kk + u*8);
      *(uint4*)&Wlds[(cI*8 + (u ^ (cI&7)))*8] = v;
    }
    __syncthreads();
    #pragma unroll
    for(int ks=0;ks<2;ks++){
      bf16x8 af[2];
      #pragma unroll
      for(int m=0;m<2;m++){
        int r = wid*32 + m*16 + (lane&15);
        int u = (ks*4 + (lane>>4)) ^ (r&7);
        af[m] = *(const bf16x8*)&Alds[(r*8+u)*8];
      }
      #pragma unroll
      for(int nb=0;nb<NB;nb++){
        int c2 = nb*16 + (lane&15);
        int u = (ks*4 + (lane>>4)) ^ (c2&7);
        bf16x8 bfv = *(const bf16x8*)&Wlds[(c2*8+u)*8];
        #pragma unroll
        for(int m=0;m<2;m++)
          acc[m][nb] = __builtin_amdgcn_mfma_f32_16x16x32_bf16(af[m], bfv, acc[m][nb], 0,0,0);
      }
    }
    __syncthreads();
  }
  #pragma unroll
  for(int nb=0;nb<NB;nb++){
    int col = nb*16 + (lane&15);
    float badd = (bias? bias[col]:0.f) + (addv? addv[col]:0.f);
    #pragma unroll
    for(int m=0;m<2;m++){
      #pragma unroll
      for(int j=0;j<4;j++){
        int row = rowBase + wid*32 + m*16 + (lane>>4)*4 + j;
        if(row<n){
          float v = acc[m][nb][j] + badd;
          if(relu) v = fmaxf(v,0.f);
          C[(size_t)row*ldc + col] = f2us(v);
        }
      }
    }
  }
}

// ------------- aggregation (R6 body; epilogue applies dis[r] to acc) -------------
__global__ __launch_bounds__(256) void k_agg(const us16* __restrict__ T,
  const int* __restrict__ csr_src, const float* __restrict__ csr_coef,
  const int* __restrict__ rp, const int* __restrict__ cnt, int rowOfs,
  const float* __restrict__ dis,
  const float* __restrict__ bias, const float* __restrict__ gamma, const float* __restrict__ beta,
  const float* __restrict__ rm, const float* __restrict__ rv,
  const us16* __restrict__ resid,
  us16* __restrict__ out, int relu, int n){
  int wid = threadIdx.x >> 6, lane = threadIdx.x & 63;
  int r = blockIdx.x*4 + wid;
  if (r >= n) return;
  int c0 = lane*2;
  int idx = rowOfs + r;
  int e0 = rp[idx], e1 = e0 + cnt[idx];
  float acc0=0.f, acc1=0.f;
  for(int e=e0;e<e1;e++){
    int s = csr_src[e];
    float c = csr_coef[e];
    unsigned int u = *(const unsigned int*)(T + (size_t)s*128 + c0);
    acc0 += c*us2f((us16)(u & 0xffffu));
    acc1 += c*us2f((us16)(u >> 16));
  }
  float disr = dis[r]; float invdeg = disr*disr;
  unsigned int uself = *(const unsigned int*)(T + (size_t)r*128 + c0);
  float o0 = acc0*disr + us2f((us16)(uself & 0xffffu))*invdeg + bias[c0];
  float o1 = acc1*disr + us2f((us16)(uself >> 16))*invdeg + bias[c0+1];
  float sc0 = gamma[c0]  * rsqrtf(rv[c0]  + 1e-5f);
  float sc1 = gamma[c0+1]* rsqrtf(rv[c0+1]+ 1e-5f);
  o0 = (o0 - rm[c0])*sc0 + beta[c0];
  o1 = (o1 - rm[c0+1])*sc1 + beta[c0+1];
  if (relu){ o0=fmaxf(o0,0.f); o1=fmaxf(o1,0.f); }
  if (resid){
    unsigned int ur = *(const unsigned int*)(resid + (size_t)r*128 + c0);
    o0 += us2f((us16)(ur & 0xffffu));
    o1 += us2f((us16)(ur >> 16));
  }
  unsigned int up = (unsigned int)f2us(o0) | ((unsigned int)f2us(o1) << 16);
  *(unsigned int*)(out + (size_t)r*128 + c0) = up;
}

// ------------- seed constant (R6-exact) -------------
__global__ void k_const64(const us16* __restrict__ X0, const us16* __restrict__ X1,
                          const int* __restrict__ seed,
                          const float* __restrict__ pw1, const float* __restrict__ pb1,
                          float* __restrict__ c64){
  int j = threadIdx.x;  // 64 threads
  int s = seed[0];
  const us16* x0 = X0 + (size_t)s*128;
  const us16* x1 = X1 + (size_t)s*128;
  float acc = pb1[j];
  for(int k=0;k<128;k++) acc += us2f(x0[k]) * pw1[(256+k)*64 + j];
  for(int k=0;k<128;k++) acc += us2f(x1[k]) * pw1[(384+k)*64 + j];
  c64[j]=acc;
}

// ------------- final dot (R6-exact) -------------
__global__ __launch_bounds__(256) void k_outdot(const us16* __restrict__ Z2, const float* __restrict__ w3,
                                                const float* __restrict__ b3, float* __restrict__ out, int n){
  int r = blockIdx.x*256 + threadIdx.x;
  if(r>=n) return;
  const us16* z = Z2 + (size_t)r*64;
  float acc = b3[0];
  #pragma unroll 8
  for(int j=0;j<64;j++) acc += us2f(z[j])*w3[j];
  out[r]=acc;
}

extern "C" void kernel_launch(void* const* d_in, const int* in_sizes, int n_in,
                              void* d_out, int out_size, void* d_ws, size_t ws_size,
                              hipStream_t stream){
  const int N = N_NODES;
  const int E = in_sizes[2];
  const float* x   = (const float*)d_in[0];
  const int*   ei  = (const int*)d_in[1];
  const int*   et  = (const int*)d_in[2];
  const float* ew  = (const float*)d_in[3];
  const int*   seed= (const int*)d_in[4];
  const float* ft_w= (const float*)d_in[5];
  const float* ft_b= (const float*)d_in[6];
  const float* g0_w= (const float*)d_in[7];
  const float* g0_b= (const float*)d_in[8];
  const float* g0_g= (const float*)d_in[9];
  const float* g0_be=(const float*)d_in[10];
  const float* g0_rm=(const float*)d_in[11];
  const float* g0_rv=(const float*)d_in[12];
  const float* g1_w= (const float*)d_in[13];
  const float* g1_b= (const float*)d_in[14];
  const float* g1_g= (const float*)d_in[15];
  const float* g1_be=(const float*)d_in[16];
  const float* g1_rm=(const float*)d_in[17];
  const float* g1_rv=(const float*)d_in[18];
  const float* p_w1= (const float*)d_in[19];
  const float* p_b1= (const float*)d_in[20];
  const float* p_w2= (const float*)d_in[21];
  const float* p_b2= (const float*)d_in[22];
  const float* p_w3= (const float*)d_in[23];
  const float* p_b3= (const float*)d_in[24];
  float* out = (float*)d_out;

  // Footprint ~118.6 MB (< R6's proven 119.2 MB).
  char* wsp = (char*)d_ws;
  auto alloc = [&](size_t bytes)->char*{ char* p = wsp; wsp += (bytes + 255) & ~(size_t)255; return p; };
  us16* B0 = (us16*)alloc((size_t)N*128*2);
  us16* B1 = (us16*)alloc((size_t)N*128*2);
  us16* B2 = (us16*)alloc((size_t)N*128*2);
  us16* B3 = (us16*)alloc((size_t)N*128*2);
  int*   csr_src  = (int*)alloc((size_t)E*4);
  float* csr_coef = (float*)alloc((size_t)E*4);
  float* disA=(float*)alloc((size_t)2*N*4);
  int* cnt =(int*)alloc((size_t)2*N*4);
  int* fill=(int*)alloc((size_t)2*N*4);
  int* rp  =(int*)alloc((size_t)2*N*4);
  int* bsum=(int*)alloc(4096);
  float* c64=(float*)alloc(256);
  us16* wt =(us16*)alloc((size_t)102400*2);
  us16* Z1 = B0;
  us16* Z2 = B1;

  const int* srcp = ei;
  const int* dstp = ei + E;

  // ---- graph preprocessing: count -> scan -> fill(w) -> deg-from-CSR -> fold dis[s] ----
  int M = 2*N;
  k_init<<<(M+255)/256,256,0,stream>>>(cnt,fill,M);
  k_cnt<<<(E+255)/256,256,0,stream>>>(dstp,et,cnt,E);
  int SB = (M+2047)/2048;
  k_scan_reduce<<<SB,256,0,stream>>>(cnt,bsum,M);
  k_scan_top<<<1,64,0,stream>>>(bsum,SB);
  k_scan_apply<<<SB,256,0,stream>>>(cnt,bsum,rp,M);
  k_edge_fill<<<(E+255)/256,256,0,stream>>>(srcp,dstp,et,ew,rp,fill,csr_src,csr_coef,E);
  k_deg_csr<<<(M+255)/256,256,0,stream>>>(csr_coef,rp,cnt,disA,M);
  k_coef<<<(E+255)/256,256,0,stream>>>(csr_src,csr_coef,rp,disA,E);

  // ---- weight prep + x conversion ----
  dim3 pg(64,7);
  k_prepw<<<pg,256,0,stream>>>(ft_w,g0_w,g1_w,p_w1,p_w2,wt);
  k_cvt<<<(N*16+255)/256,256,0,stream>>>(x, B3, N*16);

  const us16* wt_ft = wt;
  const us16* wt_g00= wt+16384;
  const us16* wt_g01= wt+32768;
  const us16* wt_g10= wt+49152;
  const us16* wt_g11= wt+65536;
  const us16* wt_p1 = wt+81920;
  const us16* wt_p2 = wt+98304;
  const float* dis0 = disA;
  const float* dis1 = disA + N;

  int GB = (N+127)/128;
  int AB = (N+3)/4;
  // ---- feature transform: B0 = relu(xb@ft_w + ft_b), xb in B3 ----
  k_mgemm<128><<<GB,256,0,stream>>>(B3,B3,128, wt_ft, ft_b, nullptr, B0,128, N,128,1);
  // ---- both blocks' layer-0 linear ----
  k_mgemm<128><<<GB,256,0,stream>>>(B0,B0,128, wt_g00, nullptr,nullptr, B1,128, N,128,0);
  k_mgemm<128><<<GB,256,0,stream>>>(B0,B0,128, wt_g10, nullptr,nullptr, B2,128, N,128,0);
  // ---- block 0 ----
  k_agg<<<AB,256,0,stream>>>(B1,csr_src,csr_coef,rp,cnt,0,dis0,
                             g0_b,g0_g,g0_be,g0_rm,g0_rv, nullptr, B0,1,N);      // h0 -> B0
  k_mgemm<128><<<GB,256,0,stream>>>(B0,B0,128, wt_g01, nullptr,nullptr, B1,128, N,128,0);
  k_agg<<<AB,256,0,stream>>>(B1,csr_src,csr_coef,rp,cnt,0,dis0,
                             g0_b+128,g0_g+128,g0_be+128,g0_rm+128,g0_rv+128, B0, B3,0,N); // x0 -> B3
  // ---- block 1 ----
  k_agg<<<AB,256,0,stream>>>(B2,csr_src,csr_coef,rp,cnt,N,dis1,
                             g1_b,g1_g,g1_be,g1_rm,g1_rv, nullptr, B0,1,N);      // h1 -> B0
  k_mgemm<128><<<GB,256,0,stream>>>(B0,B0,128, wt_g11, nullptr,nullptr, B1,128, N,128,0);
  k_agg<<<AB,256,0,stream>>>(B1,csr_src,csr_coef,rp,cnt,N,dis1,
                             g1_b+128,g1_g+128,g1_be+128,g1_rm+128,g1_rv+128, B0, B2,0,N); // x1 -> B2
  // ---- predictor ----
  k_const64<<<1,64,0,stream>>>(B3,B2,seed,p_w1,p_b1,c64);
  k_mgemm<64><<<GB,256,0,stream>>>(B3,B2,128, wt_p1, nullptr, c64, Z1,64, N,256,1);
  k_mgemm<64><<<GB,256,0,stream>>>(Z1,Z1,64,  wt_p2, p_b2, nullptr, Z2,64, N,64,1);
  k_outdot<<<(N+255)/256,256,0,stream>>>(Z2,p_w3,p_b3,out,N);
}

// Round 8
// 733.293 us; speedup vs baseline: 1.3230x; 1.0062x over previous
//
#include <hip/hip_runtime.h>
#include <hip/hip_bf16.h>
#include <stdint.h>

#define N_NODES 100000

typedef unsigned short us16;
typedef short bf16x8 __attribute__((ext_vector_type(8)));
typedef float f32x4 __attribute__((ext_vector_type(4)));

__device__ __forceinline__ float us2f(us16 u){
  union{ unsigned int i; float f; } x; x.i = ((unsigned int)u) << 16; return x.f;
}
__device__ __forceinline__ us16 f2us(float f){
  union{ float f; unsigned int i; } x; x.f = f;
  unsigned int i = x.i;
  unsigned int r = (i + 0x7FFFu + ((i >> 16) & 1u)) >> 16;
  return (us16)r;
}

// ---------------- init: zero cnt/fill ----------------
__global__ __launch_bounds__(256) void k_init(int* __restrict__ cnt, int* __restrict__ fill, int n2){
  int i = blockIdx.x*256 + threadIdx.x;
  if (i < n2){ cnt[i]=0; fill[i]=0; }
}

// ---------------- per-(type,dst) counts: ONE int atomic per edge ----------------
__global__ __launch_bounds__(256) void k_cnt(const int* __restrict__ dst,
                                             const int* __restrict__ et,
                                             int* __restrict__ cnt, int E){
  int e = blockIdx.x*256 + threadIdx.x;
  if (e>=E) return;
  int d = dst[e]; int t = et[e];
  atomicAdd(&cnt[t*N_NODES + d], 1);
}

// ---------------- exclusive scan over M elements (R1-exact) ----------------
__global__ __launch_bounds__(256) void k_scan_reduce(const int* __restrict__ in, int* __restrict__ bsum, int M){
  __shared__ int sd[256];
  int base = blockIdx.x*2048; int t = threadIdx.x;
  int sum = 0;
  #pragma unroll
  for(int i=0;i<8;i++){ int p = base + t*8 + i; if(p<M) sum += in[p]; }
  sd[t]=sum; __syncthreads();
  for(int s=128;s>0;s>>=1){ if(t<s) sd[t]+=sd[t+s]; __syncthreads(); }
  if(t==0) bsum[blockIdx.x]=sd[0];
}
__global__ void k_scan_top(int* __restrict__ bsum, int B){
  if (threadIdx.x==0){ int run=0; for(int i=0;i<B;i++){ int v=bsum[i]; bsum[i]=run; run+=v; } }
}
__global__ __launch_bounds__(256) void k_scan_apply(const int* __restrict__ in, const int* __restrict__ bsum,
                                                    int* __restrict__ out, int M){
  __shared__ int sd[256];
  int base = blockIdx.x*2048; int t = threadIdx.x;
  int loc[8]; int sum=0;
  #pragma unroll
  for(int i=0;i<8;i++){ int p = base + t*8 + i; int v = (p<M)?in[p]:0; loc[i]=sum; sum+=v; }
  sd[t]=sum; __syncthreads();
  for(int ofs=1;ofs<256;ofs<<=1){
    int v = (t>=ofs)? sd[t-ofs] : 0;
    __syncthreads();
    sd[t]+=v;
    __syncthreads();
  }
  int excl = ((t==0)?0:sd[t-1]) + bsum[blockIdx.x];
  #pragma unroll
  for(int i=0;i<8;i++){ int p = base + t*8 + i; if(p<M) out[p]=excl+loc[i]; }
}

// ---------------- CSR fill (R7-proven mechanics; uint2 payload (src, raw w)) ----------------
__global__ __launch_bounds__(256) void k_edge_fill(const int* __restrict__ src, const int* __restrict__ dst,
  const int* __restrict__ et, const float* __restrict__ ew,
  const int* __restrict__ rp, int* __restrict__ fill,
  uint2* __restrict__ csr, int E){
  int e = blockIdx.x*256+threadIdx.x;
  if(e>=E) return;
  int s=src[e], d=dst[e], t=et[e]; float w=ew[e];
  int idx = t*N_NODES + d;
  int pos = rp[idx] + atomicAdd(&fill[idx],1);
  csr[pos] = make_uint2((unsigned)s, __float_as_uint(w));
}

// ---------------- degree from CSR (sequential, atomic-free) ----------------
__global__ __launch_bounds__(256) void k_deg_csr(const uint2* __restrict__ csr,
                                                 const int* __restrict__ rp, const int* __restrict__ cnt,
                                                 float* __restrict__ disA, int M){
  int i = blockIdx.x*256+threadIdx.x;
  if(i>=M) return;
  int e0 = rp[i], c = cnt[i];
  float s = 1.0f;
  for(int e=e0; e<e0+c; e++) s += __uint_as_float(csr[e].y);
  disA[i] = rsqrtf(s);
}

// ---------------- fold dis[src] into coefficients: coef = w * dis[s] ----------------
__global__ __launch_bounds__(256) void k_coef(uint2* __restrict__ csr,
                                              const int* __restrict__ rp,
                                              const float* __restrict__ disA, int E){
  int e = blockIdx.x*256+threadIdx.x;
  if(e>=E) return;
  int rpN = rp[N_NODES];               // boundary: first type-1 entry
  int t = (e >= rpN) ? 1 : 0;
  uint2 q = csr[e];
  float w = __uint_as_float(q.y) * disA[t*N_NODES + (int)q.x];
  csr[e] = make_uint2(q.x, __float_as_uint(w));
}

// ---------------- weight prep: f32 [K][NC] -> bf16 transposed [NC][K] ----------------
__global__ __launch_bounds__(256) void k_prepw(const float* __restrict__ ft_w,
                                               const float* __restrict__ g0_w, const float* __restrict__ g1_w,
                                               const float* __restrict__ p_w1, const float* __restrict__ p_w2,
                                               us16* __restrict__ wt){
  int m = blockIdx.y;
  const float* srcp; int K, NCc; us16* dstp;
  switch(m){
    case 0: srcp=ft_w;        K=128; NCc=128; dstp=wt;        break;
    case 1: srcp=g0_w;        K=128; NCc=128; dstp=wt+16384;  break;
    case 2: srcp=g0_w+16384;  K=128; NCc=128; dstp=wt+32768;  break;
    case 3: srcp=g1_w;        K=128; NCc=128; dstp=wt+49152;  break;
    case 4: srcp=g1_w+16384;  K=128; NCc=128; dstp=wt+65536;  break;
    case 5: srcp=p_w1;        K=256; NCc=64;  dstp=wt+81920;  break;
    default:srcp=p_w2;        K=64;  NCc=64;  dstp=wt+98304;  break;
  }
  int idx = blockIdx.x*256+threadIdx.x;
  if(idx >= K*NCc) return;
  int nn = idx / K, k = idx - nn*K;
  dstp[idx] = f2us(srcp[(size_t)k*NCc + nn]);
}

// ---------- MFMA GEMM (R6-verified core): C[n,NC](bf16) = A@W (+bias/addv, relu) ----------
// A element type templated: us16 (bf16) or float (converted during staging, same f2us rounding).
template<int NC, typename AT>
__global__ __launch_bounds__(256) void k_mgemm(const AT* __restrict__ A0, const AT* __restrict__ A1,
                 int lda, const us16* __restrict__ Wt,
                 const float* __restrict__ bias, const float* __restrict__ addv,
                 us16* __restrict__ C, int ldc, int n, int KC, int relu){
  constexpr int NB = NC/16;
  __shared__ us16 Alds[128*64];
  __shared__ us16 Wlds[NC*64];
  const int tid = threadIdx.x;
  const int lane = tid & 63, wid = tid >> 6;
  const int rowBase = blockIdx.x*128;
  f32x4 zero = {0.f,0.f,0.f,0.f};
  f32x4 acc[2][NB];
  #pragma unroll
  for(int m=0;m<2;m++)
    #pragma unroll
    for(int nb=0;nb<NB;nb++) acc[m][nb] = zero;

  for(int kk=0; kk<KC; kk+=64){
    const AT* Ab = (kk<128)? A0 : A1;
    const int kc = (kk<128)? kk : (kk-128);
    #pragma unroll
    for(int p=0;p<4;p++){
      int idx = p*256 + tid;
      int r = idx>>3, u = idx&7;
      int row = rowBase + r;
      uint4 v = make_uint4(0u,0u,0u,0u);
      if(row<n){
        if constexpr (sizeof(AT)==2){
          v = *(const uint4*)(Ab + (size_t)row*lda + kc + u*8);
        } else {
          float4 f0 = *(const float4*)(Ab + (size_t)row*lda + kc + u*8);
          float4 f1 = *(const float4*)(Ab + (size_t)row*lda + kc + u*8 + 4);
          us16 tmp[8] = {f2us(f0.x),f2us(f0.y),f2us(f0.z),f2us(f0.w),
                         f2us(f1.x),f2us(f1.y),f2us(f1.z),f2us(f1.w)};
          v = *(const uint4*)tmp;
        }
      }
      *(uint4*)&Alds[(r*8 + (u ^ (r&7)))*8] = v;
    }
    #pragma unroll
    for(int p=0;p<NB/2;p++){
      int idx = p*256 + tid;
      int cI = idx>>3, u = idx&7;
      uint4 v = *(const uint4*)(Wt + (size_t)cI*KC + kk + u*8);
      *(uint4*)&Wlds[(cI*8 + (u ^ (cI&7)))*8] = v;
    }
    __syncthreads();
    #pragma unroll
    for(int ks=0;ks<2;ks++){
      bf16x8 af[2];
      #pragma unroll
      for(int m=0;m<2;m++){
        int r = wid*32 + m*16 + (lane&15);
        int u = (ks*4 + (lane>>4)) ^ (r&7);
        af[m] = *(const bf16x8*)&Alds[(r*8+u)*8];
      }
      #pragma unroll
      for(int nb=0;nb<NB;nb++){
        int c2 = nb*16 + (lane&15);
        int u = (ks*4 + (lane>>4)) ^ (c2&7);
        bf16x8 bfv = *(const bf16x8*)&Wlds[(c2*8+u)*8];
        #pragma unroll
        for(int m=0;m<2;m++)
          acc[m][nb] = __builtin_amdgcn_mfma_f32_16x16x32_bf16(af[m], bfv, acc[m][nb], 0,0,0);
      }
    }
    __syncthreads();
  }
  #pragma unroll
  for(int nb=0;nb<NB;nb++){
    int col = nb*16 + (lane&15);
    float badd = (bias? bias[col]:0.f) + (addv? addv[col]:0.f);
    #pragma unroll
    for(int m=0;m<2;m++){
      #pragma unroll
      for(int j=0;j<4;j++){
        int row = rowBase + wid*32 + m*16 + (lane>>4)*4 + j;
        if(row<n){
          float v = acc[m][nb][j] + badd;
          if(relu) v = fmaxf(v,0.f);
          C[(size_t)row*ldc + col] = f2us(v);
        }
      }
    }
  }
}

// ------------- aggregation (R7 body; uint2 CSR read; NO unroll) -------------
__global__ __launch_bounds__(256) void k_agg(const us16* __restrict__ T,
  const uint2* __restrict__ csr,
  const int* __restrict__ rp, const int* __restrict__ cnt, int rowOfs,
  const float* __restrict__ dis,
  const float* __restrict__ bias, const float* __restrict__ gamma, const float* __restrict__ beta,
  const float* __restrict__ rm, const float* __restrict__ rv,
  const us16* __restrict__ resid,
  us16* __restrict__ out, int relu, int n){
  int wid = threadIdx.x >> 6, lane = threadIdx.x & 63;
  int r = blockIdx.x*4 + wid;
  if (r >= n) return;
  int c0 = lane*2;
  int idx = rowOfs + r;
  int e0 = rp[idx], e1 = e0 + cnt[idx];
  float acc0=0.f, acc1=0.f;
  for(int e=e0;e<e1;e++){
    uint2 q = csr[e];
    float c = __uint_as_float(q.y);
    unsigned int u = *(const unsigned int*)(T + (size_t)q.x*128 + c0);
    acc0 += c*us2f((us16)(u & 0xffffu));
    acc1 += c*us2f((us16)(u >> 16));
  }
  float disr = dis[r]; float invdeg = disr*disr;
  unsigned int uself = *(const unsigned int*)(T + (size_t)r*128 + c0);
  float o0 = acc0*disr + us2f((us16)(uself & 0xffffu))*invdeg + bias[c0];
  float o1 = acc1*disr + us2f((us16)(uself >> 16))*invdeg + bias[c0+1];
  float sc0 = gamma[c0]  * rsqrtf(rv[c0]  + 1e-5f);
  float sc1 = gamma[c0+1]* rsqrtf(rv[c0+1]+ 1e-5f);
  o0 = (o0 - rm[c0])*sc0 + beta[c0];
  o1 = (o1 - rm[c0+1])*sc1 + beta[c0+1];
  if (relu){ o0=fmaxf(o0,0.f); o1=fmaxf(o1,0.f); }
  if (resid){
    unsigned int ur = *(const unsigned int*)(resid + (size_t)r*128 + c0);
    o0 += us2f((us16)(ur & 0xffffu));
    o1 += us2f((us16)(ur >> 16));
  }
  unsigned int up = (unsigned int)f2us(o0) | ((unsigned int)f2us(o1) << 16);
  *(unsigned int*)(out + (size_t)r*128 + c0) = up;
}

// ------------- seed constant (R7-exact) -------------
__global__ void k_const64(const us16* __restrict__ X0, const us16* __restrict__ X1,
                          const int* __restrict__ seed,
                          const float* __restrict__ pw1, const float* __restrict__ pb1,
                          float* __restrict__ c64){
  int j = threadIdx.x;  // 64 threads
  int s = seed[0];
  const us16* x0 = X0 + (size_t)s*128;
  const us16* x1 = X1 + (size_t)s*128;
  float acc = pb1[j];
  for(int k=0;k<128;k++) acc += us2f(x0[k]) * pw1[(256+k)*64 + j];
  for(int k=0;k<128;k++) acc += us2f(x1[k]) * pw1[(384+k)*64 + j];
  c64[j]=acc;
}

// ------------- final dot (R7-exact) -------------
__global__ __launch_bounds__(256) void k_outdot(const us16* __restrict__ Z2, const float* __restrict__ w3,
                                                const float* __restrict__ b3, float* __restrict__ out, int n){
  int r = blockIdx.x*256 + threadIdx.x;
  if(r>=n) return;
  const us16* z = Z2 + (size_t)r*64;
  float acc = b3[0];
  #pragma unroll 8
  for(int j=0;j<64;j++) acc += us2f(z[j])*w3[j];
  out[r]=acc;
}

extern "C" void kernel_launch(void* const* d_in, const int* in_sizes, int n_in,
                              void* d_out, int out_size, void* d_ws, size_t ws_size,
                              hipStream_t stream){
  const int N = N_NODES;
  const int E = in_sizes[2];
  const float* x   = (const float*)d_in[0];
  const int*   ei  = (const int*)d_in[1];
  const int*   et  = (const int*)d_in[2];
  const float* ew  = (const float*)d_in[3];
  const int*   seed= (const int*)d_in[4];
  const float* ft_w= (const float*)d_in[5];
  const float* ft_b= (const float*)d_in[6];
  const float* g0_w= (const float*)d_in[7];
  const float* g0_b= (const float*)d_in[8];
  const float* g0_g= (const float*)d_in[9];
  const float* g0_be=(const float*)d_in[10];
  const float* g0_rm=(const float*)d_in[11];
  const float* g0_rv=(const float*)d_in[12];
  const float* g1_w= (const float*)d_in[13];
  const float* g1_b= (const float*)d_in[14];
  const float* g1_g= (const float*)d_in[15];
  const float* g1_be=(const float*)d_in[16];
  const float* g1_rm=(const float*)d_in[17];
  const float* g1_rv=(const float*)d_in[18];
  const float* p_w1= (const float*)d_in[19];
  const float* p_b1= (const float*)d_in[20];
  const float* p_w2= (const float*)d_in[21];
  const float* p_b2= (const float*)d_in[22];
  const float* p_w3= (const float*)d_in[23];
  const float* p_b3= (const float*)d_in[24];
  float* out = (float*)d_out;

  // Footprint ~118.6 MB (same as proven R7).
  char* wsp = (char*)d_ws;
  auto alloc = [&](size_t bytes)->char*{ char* p = wsp; wsp += (bytes + 255) & ~(size_t)255; return p; };
  us16* B0 = (us16*)alloc((size_t)N*128*2);
  us16* B1 = (us16*)alloc((size_t)N*128*2);
  us16* B2 = (us16*)alloc((size_t)N*128*2);
  us16* B3 = (us16*)alloc((size_t)N*128*2);
  uint2* csr = (uint2*)alloc((size_t)E*8);
  float* disA=(float*)alloc((size_t)2*N*4);
  int* cnt =(int*)alloc((size_t)2*N*4);
  int* fill=(int*)alloc((size_t)2*N*4);
  int* rp  =(int*)alloc((size_t)2*N*4);
  int* bsum=(int*)alloc(4096);
  float* c64=(float*)alloc(256);
  us16* wt =(us16*)alloc((size_t)102400*2);
  us16* Z1 = B0;
  us16* Z2 = B1;

  const int* srcp = ei;
  const int* dstp = ei + E;

  // ---- graph preprocessing: count -> scan -> fill(s,w) -> deg-from-CSR -> fold dis[s] ----
  int M = 2*N;
  k_init<<<(M+255)/256,256,0,stream>>>(cnt,fill,M);
  k_cnt<<<(E+255)/256,256,0,stream>>>(dstp,et,cnt,E);
  int SB = (M+2047)/2048;
  k_scan_reduce<<<SB,256,0,stream>>>(cnt,bsum,M);
  k_scan_top<<<1,64,0,stream>>>(bsum,SB);
  k_scan_apply<<<SB,256,0,stream>>>(cnt,bsum,rp,M);
  k_edge_fill<<<(E+255)/256,256,0,stream>>>(srcp,dstp,et,ew,rp,fill,csr,E);
  k_deg_csr<<<(M+255)/256,256,0,stream>>>(csr,rp,cnt,disA,M);
  k_coef<<<(E+255)/256,256,0,stream>>>(csr,rp,disA,E);

  // ---- weight prep ----
  dim3 pg(64,7);
  k_prepw<<<pg,256,0,stream>>>(ft_w,g0_w,g1_w,p_w1,p_w2,wt);

  const us16* wt_ft = wt;
  const us16* wt_g00= wt+16384;
  const us16* wt_g01= wt+32768;
  const us16* wt_g10= wt+49152;
  const us16* wt_g11= wt+65536;
  const us16* wt_p1 = wt+81920;
  const us16* wt_p2 = wt+98304;
  const float* dis0 = disA;
  const float* dis1 = disA + N;

  int GB = (N+127)/128;
  int AB = (N+3)/4;
  // ---- feature transform: B0 = relu(x@ft_w + ft_b), f32 x staged directly ----
  k_mgemm<128,float><<<GB,256,0,stream>>>(x,x,128, wt_ft, ft_b, nullptr, B0,128, N,128,1);
  // ---- both blocks' layer-0 linear ----
  k_mgemm<128,us16><<<GB,256,0,stream>>>(B0,B0,128, wt_g00, nullptr,nullptr, B1,128, N,128,0);
  k_mgemm<128,us16><<<GB,256,0,stream>>>(B0,B0,128, wt_g10, nullptr,nullptr, B2,128, N,128,0);
  // ---- block 0 ----
  k_agg<<<AB,256,0,stream>>>(B1,csr,rp,cnt,0,dis0,
                             g0_b,g0_g,g0_be,g0_rm,g0_rv, nullptr, B0,1,N);      // h0 -> B0
  k_mgemm<128,us16><<<GB,256,0,stream>>>(B0,B0,128, wt_g01, nullptr,nullptr, B1,128, N,128,0);
  k_agg<<<AB,256,0,stream>>>(B1,csr,rp,cnt,0,dis0,
                             g0_b+128,g0_g+128,g0_be+128,g0_rm+128,g0_rv+128, B0, B3,0,N); // x0 -> B3
  // ---- block 1 ----
  k_agg<<<AB,256,0,stream>>>(B2,csr,rp,cnt,N,dis1,
                             g1_b,g1_g,g1_be,g1_rm,g1_rv, nullptr, B0,1,N);      // h1 -> B0
  k_mgemm<128,us16><<<GB,256,0,stream>>>(B0,B0,128, wt_g11, nullptr,nullptr, B1,128, N,128,0);
  k_agg<<<AB,256,0,stream>>>(B1,csr,rp,cnt,N,dis1,
                             g1_b+128,g1_g+128,g1_be+128,g1_rm+128,g1_rv+128, B0, B2,0,N); // x1 -> B2
  // ---- predictor ----
  k_const64<<<1,64,0,stream>>>(B3,B2,seed,p_w1,p_b1,c64);
  k_mgemm<64,us16><<<GB,256,0,stream>>>(B3,B2,128, wt_p1, nullptr, c64, Z1,64, N,256,1);
  k_mgemm<64,us16><<<GB,256,0,stream>>>(Z1,Z1,64,  wt_p2, p_b2, nullptr, Z2,64, N,64,1);
  k_outdot<<<(N+255)/256,256,0,stream>>>(Z2,p_w3,p_b3,out,N);
}

// Round 9
// 503.788 us; speedup vs baseline: 1.9258x; 1.4556x over previous
//
#include <hip/hip_runtime.h>
#include <hip/hip_bf16.h>
#include <stdint.h>

#define N_NODES 100000

typedef unsigned short us16;
typedef short bf16x8 __attribute__((ext_vector_type(8)));
typedef float f32x4 __attribute__((ext_vector_type(4)));

__device__ __forceinline__ float us2f(us16 u){
  union{ unsigned int i; float f; } x; x.i = ((unsigned int)u) << 16; return x.f;
}
__device__ __forceinline__ us16 f2us(float f){
  union{ float f; unsigned int i; } x; x.f = f;
  unsigned int i = x.i;
  unsigned int r = (i + 0x7FFFu + ((i >> 16) & 1u)) >> 16;
  return (us16)r;
}

// ---------------- init: zero cnt ----------------
__global__ __launch_bounds__(256) void k_init(int* __restrict__ cnt, int n2){
  int i = blockIdx.x*256 + threadIdx.x;
  if (i < n2) cnt[i]=0;
}

// ------- per-(type,dst) counts: ONE int atomic per edge; rank stored coalesced -------
__global__ __launch_bounds__(256) void k_cnt(const int* __restrict__ dst,
                                             const int* __restrict__ et,
                                             int* __restrict__ cnt,
                                             int* __restrict__ eofs, int E){
  int e = blockIdx.x*256 + threadIdx.x;
  if (e>=E) return;
  int d = dst[e]; int t = et[e];
  eofs[e] = atomicAdd(&cnt[t*N_NODES + d], 1);
}

// ---------------- exclusive scan over M elements (R1-exact) ----------------
__global__ __launch_bounds__(256) void k_scan_reduce(const int* __restrict__ in, int* __restrict__ bsum, int M){
  __shared__ int sd[256];
  int base = blockIdx.x*2048; int t = threadIdx.x;
  int sum = 0;
  #pragma unroll
  for(int i=0;i<8;i++){ int p = base + t*8 + i; if(p<M) sum += in[p]; }
  sd[t]=sum; __syncthreads();
  for(int s=128;s>0;s>>=1){ if(t<s) sd[t]+=sd[t+s]; __syncthreads(); }
  if(t==0) bsum[blockIdx.x]=sd[0];
}
__global__ void k_scan_top(int* __restrict__ bsum, int B){
  if (threadIdx.x==0){ int run=0; for(int i=0;i<B;i++){ int v=bsum[i]; bsum[i]=run; run+=v; } }
}
__global__ __launch_bounds__(256) void k_scan_apply(const int* __restrict__ in, const int* __restrict__ bsum,
                                                    int* __restrict__ out, int M){
  __shared__ int sd[256];
  int base = blockIdx.x*2048; int t = threadIdx.x;
  int loc[8]; int sum=0;
  #pragma unroll
  for(int i=0;i<8;i++){ int p = base + t*8 + i; int v = (p<M)?in[p]:0; loc[i]=sum; sum+=v; }
  sd[t]=sum; __syncthreads();
  for(int ofs=1;ofs<256;ofs<<=1){
    int v = (t>=ofs)? sd[t-ofs] : 0;
    __syncthreads();
    sd[t]+=v;
    __syncthreads();
  }
  int excl = ((t==0)?0:sd[t-1]) + bsum[blockIdx.x];
  #pragma unroll
  for(int i=0;i<8;i++){ int p = base + t*8 + i; if(p<M) out[p]=excl+loc[i]; }
}

// ---------------- CSR fill: NO atomic (pos = rp + precomputed rank) ----------------
__global__ __launch_bounds__(256) void k_edge_fill(const int* __restrict__ src, const int* __restrict__ dst,
  const int* __restrict__ et, const float* __restrict__ ew,
  const int* __restrict__ rp, const int* __restrict__ eofs,
  uint2* __restrict__ csr, int E){
  int e = blockIdx.x*256+threadIdx.x;
  if(e>=E) return;
  int s=src[e], d=dst[e], t=et[e]; float w=ew[e];
  int idx = t*N_NODES + d;
  int pos = rp[idx] + eofs[e];
  csr[pos] = make_uint2((unsigned)s, __float_as_uint(w));
}

// ---------------- degree from CSR (sequential, atomic-free) ----------------
__global__ __launch_bounds__(256) void k_deg_csr(const uint2* __restrict__ csr,
                                                 const int* __restrict__ rp, const int* __restrict__ cnt,
                                                 float* __restrict__ disA, int M){
  int i = blockIdx.x*256+threadIdx.x;
  if(i>=M) return;
  int e0 = rp[i], c = cnt[i];
  float s = 1.0f;
  for(int e=e0; e<e0+c; e++) s += __uint_as_float(csr[e].y);
  disA[i] = rsqrtf(s);
}

// ---------------- fold dis[src] into coefficients: coef = w * dis[s] ----------------
__global__ __launch_bounds__(256) void k_coef(uint2* __restrict__ csr,
                                              const int* __restrict__ rp,
                                              const float* __restrict__ disA, int E){
  int e = blockIdx.x*256+threadIdx.x;
  if(e>=E) return;
  int rpN = rp[N_NODES];               // boundary: first type-1 entry
  int t = (e >= rpN) ? 1 : 0;
  uint2 q = csr[e];
  float w = __uint_as_float(q.y) * disA[t*N_NODES + (int)q.x];
  csr[e] = make_uint2(q.x, __float_as_uint(w));
}

// ---------------- weight prep: f32 [K][NC] -> bf16 transposed [NC][K] ----------------
__global__ __launch_bounds__(256) void k_prepw(const float* __restrict__ ft_w,
                                               const float* __restrict__ g0_w, const float* __restrict__ g1_w,
                                               const float* __restrict__ p_w1, const float* __restrict__ p_w2,
                                               us16* __restrict__ wt){
  int m = blockIdx.y;
  const float* srcp; int K, NCc; us16* dstp;
  switch(m){
    case 0: srcp=ft_w;        K=128; NCc=128; dstp=wt;        break;
    case 1: srcp=g0_w;        K=128; NCc=128; dstp=wt+16384;  break;
    case 2: srcp=g0_w+16384;  K=128; NCc=128; dstp=wt+32768;  break;
    case 3: srcp=g1_w;        K=128; NCc=128; dstp=wt+49152;  break;
    case 4: srcp=g1_w+16384;  K=128; NCc=128; dstp=wt+65536;  break;
    case 5: srcp=p_w1;        K=256; NCc=64;  dstp=wt+81920;  break;
    default:srcp=p_w2;        K=64;  NCc=64;  dstp=wt+98304;  break;
  }
  int idx = blockIdx.x*256+threadIdx.x;
  if(idx >= K*NCc) return;
  int nn = idx / K, k = idx - nn*K;
  dstp[idx] = f2us(srcp[(size_t)k*NCc + nn]);
}

// ---------- MFMA GEMM (R6-verified core): C[n,NC](bf16) = A@W (+bias/addv, relu) ----------
template<int NC, typename AT>
__global__ __launch_bounds__(256) void k_mgemm(const AT* __restrict__ A0, const AT* __restrict__ A1,
                 int lda, const us16* __restrict__ Wt,
                 const float* __restrict__ bias, const float* __restrict__ addv,
                 us16* __restrict__ C, int ldc, int n, int KC, int relu){
  constexpr int NB = NC/16;
  __shared__ us16 Alds[128*64];
  __shared__ us16 Wlds[NC*64];
  const int tid = threadIdx.x;
  const int lane = tid & 63, wid = tid >> 6;
  const int rowBase = blockIdx.x*128;
  f32x4 zero = {0.f,0.f,0.f,0.f};
  f32x4 acc[2][NB];
  #pragma unroll
  for(int m=0;m<2;m++)
    #pragma unroll
    for(int nb=0;nb<NB;nb++) acc[m][nb] = zero;

  for(int kk=0; kk<KC; kk+=64){
    const AT* Ab = (kk<128)? A0 : A1;
    const int kc = (kk<128)? kk : (kk-128);
    #pragma unroll
    for(int p=0;p<4;p++){
      int idx = p*256 + tid;
      int r = idx>>3, u = idx&7;
      int row = rowBase + r;
      uint4 v = make_uint4(0u,0u,0u,0u);
      if(row<n){
        if constexpr (sizeof(AT)==2){
          v = *(const uint4*)(Ab + (size_t)row*lda + kc + u*8);
        } else {
          float4 f0 = *(const float4*)(Ab + (size_t)row*lda + kc + u*8);
          float4 f1 = *(const float4*)(Ab + (size_t)row*lda + kc + u*8 + 4);
          us16 tmp[8] = {f2us(f0.x),f2us(f0.y),f2us(f0.z),f2us(f0.w),
                         f2us(f1.x),f2us(f1.y),f2us(f1.z),f2us(f1.w)};
          v = *(const uint4*)tmp;
        }
      }
      *(uint4*)&Alds[(r*8 + (u ^ (r&7)))*8] = v;
    }
    #pragma unroll
    for(int p=0;p<NB/2;p++){
      int idx = p*256 + tid;
      int cI = idx>>3, u = idx&7;
      uint4 v = *(const uint4*)(Wt + (size_t)cI*KC + kk + u*8);
      *(uint4*)&Wlds[(cI*8 + (u ^ (cI&7)))*8] = v;
    }
    __syncthreads();
    #pragma unroll
    for(int ks=0;ks<2;ks++){
      bf16x8 af[2];
      #pragma unroll
      for(int m=0;m<2;m++){
        int r = wid*32 + m*16 + (lane&15);
        int u = (ks*4 + (lane>>4)) ^ (r&7);
        af[m] = *(const bf16x8*)&Alds[(r*8+u)*8];
      }
      #pragma unroll
      for(int nb=0;nb<NB;nb++){
        int c2 = nb*16 + (lane&15);
        int u = (ks*4 + (lane>>4)) ^ (c2&7);
        bf16x8 bfv = *(const bf16x8*)&Wlds[(c2*8+u)*8];
        #pragma unroll
        for(int m=0;m<2;m++)
          acc[m][nb] = __builtin_amdgcn_mfma_f32_16x16x32_bf16(af[m], bfv, acc[m][nb], 0,0,0);
      }
    }
    __syncthreads();
  }
  #pragma unroll
  for(int nb=0;nb<NB;nb++){
    int col = nb*16 + (lane&15);
    float badd = (bias? bias[col]:0.f) + (addv? addv[col]:0.f);
    #pragma unroll
    for(int m=0;m<2;m++){
      #pragma unroll
      for(int j=0;j<4;j++){
        int row = rowBase + wid*32 + m*16 + (lane>>4)*4 + j;
        if(row<n){
          float v = acc[m][nb][j] + badd;
          if(relu) v = fmaxf(v,0.f);
          C[(size_t)row*ldc + col] = f2us(v);
        }
      }
    }
  }
}

// ------------- aggregation: chunk-4 independent gathers (latency batching) -------------
__global__ __launch_bounds__(256) void k_agg(const us16* __restrict__ T,
  const uint2* __restrict__ csr,
  const int* __restrict__ rp, const int* __restrict__ cnt, int rowOfs,
  const float* __restrict__ dis,
  const float* __restrict__ bias, const float* __restrict__ gamma, const float* __restrict__ beta,
  const float* __restrict__ rm, const float* __restrict__ rv,
  const us16* __restrict__ resid,
  us16* __restrict__ out, int relu, int n){
  int wid = threadIdx.x >> 6, lane = threadIdx.x & 63;
  int r = blockIdx.x*4 + wid;
  if (r >= n) return;
  int c0 = lane*2;
  int idx = rowOfs + r;
  int e0 = rp[idx];
  int ec = cnt[idx];
  const uint2* cp = csr + e0;
  float acc0=0.f, acc1=0.f;
  int nchunk = ec >> 2;
  int rem = ec & 3;
  for(int ch=0; ch<nchunk; ch++){
    uint2 q0 = cp[0], q1 = cp[1], q2 = cp[2], q3 = cp[3];
    cp += 4;
    unsigned ua = *(const unsigned int*)(T + (size_t)q0.x*128 + c0);
    unsigned ub = *(const unsigned int*)(T + (size_t)q1.x*128 + c0);
    unsigned uc = *(const unsigned int*)(T + (size_t)q2.x*128 + c0);
    unsigned ud = *(const unsigned int*)(T + (size_t)q3.x*128 + c0);
    float ca = __uint_as_float(q0.y), cb = __uint_as_float(q1.y);
    float cc = __uint_as_float(q2.y), cd = __uint_as_float(q3.y);
    acc0 += ca*us2f((us16)(ua & 0xffffu));
    acc1 += ca*us2f((us16)(ua >> 16));
    acc0 += cb*us2f((us16)(ub & 0xffffu));
    acc1 += cb*us2f((us16)(ub >> 16));
    acc0 += cc*us2f((us16)(uc & 0xffffu));
    acc1 += cc*us2f((us16)(uc >> 16));
    acc0 += cd*us2f((us16)(ud & 0xffffu));
    acc1 += cd*us2f((us16)(ud >> 16));
  }
  for(int i=0;i<rem;i++){
    uint2 q = cp[i];
    float c = __uint_as_float(q.y);
    unsigned u = *(const unsigned int*)(T + (size_t)q.x*128 + c0);
    acc0 += c*us2f((us16)(u & 0xffffu));
    acc1 += c*us2f((us16)(u >> 16));
  }
  float disr = dis[r]; float invdeg = disr*disr;
  unsigned int uself = *(const unsigned int*)(T + (size_t)r*128 + c0);
  float o0 = acc0*disr + us2f((us16)(uself & 0xffffu))*invdeg + bias[c0];
  float o1 = acc1*disr + us2f((us16)(uself >> 16))*invdeg + bias[c0+1];
  float sc0 = gamma[c0]  * rsqrtf(rv[c0]  + 1e-5f);
  float sc1 = gamma[c0+1]* rsqrtf(rv[c0+1]+ 1e-5f);
  o0 = (o0 - rm[c0])*sc0 + beta[c0];
  o1 = (o1 - rm[c0+1])*sc1 + beta[c0+1];
  if (relu){ o0=fmaxf(o0,0.f); o1=fmaxf(o1,0.f); }
  if (resid){
    unsigned int ur = *(const unsigned int*)(resid + (size_t)r*128 + c0);
    o0 += us2f((us16)(ur & 0xffffu));
    o1 += us2f((us16)(ur >> 16));
  }
  unsigned int up = (unsigned int)f2us(o0) | ((unsigned int)f2us(o1) << 16);
  *(unsigned int*)(out + (size_t)r*128 + c0) = up;
}

// ------------- seed constant (R8-exact) -------------
__global__ void k_const64(const us16* __restrict__ X0, const us16* __restrict__ X1,
                          const int* __restrict__ seed,
                          const float* __restrict__ pw1, const float* __restrict__ pb1,
                          float* __restrict__ c64){
  int j = threadIdx.x;  // 64 threads
  int s = seed[0];
  const us16* x0 = X0 + (size_t)s*128;
  const us16* x1 = X1 + (size_t)s*128;
  float acc = pb1[j];
  #pragma unroll 8
  for(int k=0;k<128;k++) acc += us2f(x0[k]) * pw1[(256+k)*64 + j];
  #pragma unroll 8
  for(int k=0;k<128;k++) acc += us2f(x1[k]) * pw1[(384+k)*64 + j];
  c64[j]=acc;
}

// ------------- final dot (R8-exact) -------------
__global__ __launch_bounds__(256) void k_outdot(const us16* __restrict__ Z2, const float* __restrict__ w3,
                                                const float* __restrict__ b3, float* __restrict__ out, int n){
  int r = blockIdx.x*256 + threadIdx.x;
  if(r>=n) return;
  const us16* z = Z2 + (size_t)r*64;
  float acc = b3[0];
  #pragma unroll 8
  for(int j=0;j<64;j++) acc += us2f(z[j])*w3[j];
  out[r]=acc;
}

extern "C" void kernel_launch(void* const* d_in, const int* in_sizes, int n_in,
                              void* d_out, int out_size, void* d_ws, size_t ws_size,
                              hipStream_t stream){
  const int N = N_NODES;
  const int E = in_sizes[2];
  const float* x   = (const float*)d_in[0];
  const int*   ei  = (const int*)d_in[1];
  const int*   et  = (const int*)d_in[2];
  const float* ew  = (const float*)d_in[3];
  const int*   seed= (const int*)d_in[4];
  const float* ft_w= (const float*)d_in[5];
  const float* ft_b= (const float*)d_in[6];
  const float* g0_w= (const float*)d_in[7];
  const float* g0_b= (const float*)d_in[8];
  const float* g0_g= (const float*)d_in[9];
  const float* g0_be=(const float*)d_in[10];
  const float* g0_rm=(const float*)d_in[11];
  const float* g0_rv=(const float*)d_in[12];
  const float* g1_w= (const float*)d_in[13];
  const float* g1_b= (const float*)d_in[14];
  const float* g1_g= (const float*)d_in[15];
  const float* g1_be=(const float*)d_in[16];
  const float* g1_rm=(const float*)d_in[17];
  const float* g1_rv=(const float*)d_in[18];
  const float* p_w1= (const float*)d_in[19];
  const float* p_b1= (const float*)d_in[20];
  const float* p_w2= (const float*)d_in[21];
  const float* p_b2= (const float*)d_in[22];
  const float* p_w3= (const float*)d_in[23];
  const float* p_b3= (const float*)d_in[24];
  float* out = (float*)d_out;

  // Footprint ~117.8 MB (< proven 119.2 MB). eofs aliases dead B0.
  char* wsp = (char*)d_ws;
  auto alloc = [&](size_t bytes)->char*{ char* p = wsp; wsp += (bytes + 255) & ~(size_t)255; return p; };
  us16* B0 = (us16*)alloc((size_t)N*128*2);
  us16* B1 = (us16*)alloc((size_t)N*128*2);
  us16* B2 = (us16*)alloc((size_t)N*128*2);
  us16* B3 = (us16*)alloc((size_t)N*128*2);
  uint2* csr = (uint2*)alloc((size_t)E*8);
  float* disA=(float*)alloc((size_t)2*N*4);
  int* cnt =(int*)alloc((size_t)2*N*4);
  int* rp  =(int*)alloc((size_t)2*N*4);
  int* bsum=(int*)alloc(4096);
  float* c64=(float*)alloc(256);
  us16* wt =(us16*)alloc((size_t)102400*2);
  int* eofs = (int*)B0;          // E*4 = 6.4MB <= B0's 25.6MB; B0 first written after fill
  us16* Z1 = B0;
  us16* Z2 = B1;

  const int* srcp = ei;
  const int* dstp = ei + E;

  // ---- graph preprocessing: count(+rank) -> scan -> fill(no atomic) -> deg -> fold dis[s] ----
  int M = 2*N;
  k_init<<<(M+255)/256,256,0,stream>>>(cnt,M);
  k_cnt<<<(E+255)/256,256,0,stream>>>(dstp,et,cnt,eofs,E);
  int SB = (M+2047)/2048;
  k_scan_reduce<<<SB,256,0,stream>>>(cnt,bsum,M);
  k_scan_top<<<1,64,0,stream>>>(bsum,SB);
  k_scan_apply<<<SB,256,0,stream>>>(cnt,bsum,rp,M);
  k_edge_fill<<<(E+255)/256,256,0,stream>>>(srcp,dstp,et,ew,rp,eofs,csr,E);
  k_deg_csr<<<(M+255)/256,256,0,stream>>>(csr,rp,cnt,disA,M);
  k_coef<<<(E+255)/256,256,0,stream>>>(csr,rp,disA,E);

  // ---- weight prep ----
  dim3 pg(64,7);
  k_prepw<<<pg,256,0,stream>>>(ft_w,g0_w,g1_w,p_w1,p_w2,wt);

  const us16* wt_ft = wt;
  const us16* wt_g00= wt+16384;
  const us16* wt_g01= wt+32768;
  const us16* wt_g10= wt+49152;
  const us16* wt_g11= wt+65536;
  const us16* wt_p1 = wt+81920;
  const us16* wt_p2 = wt+98304;
  const float* dis0 = disA;
  const float* dis1 = disA + N;

  int GB = (N+127)/128;
  int AB = (N+3)/4;
  // ---- feature transform: B0 = relu(x@ft_w + ft_b), f32 x staged directly ----
  k_mgemm<128,float><<<GB,256,0,stream>>>(x,x,128, wt_ft, ft_b, nullptr, B0,128, N,128,1);
  // ---- both blocks' layer-0 linear ----
  k_mgemm<128,us16><<<GB,256,0,stream>>>(B0,B0,128, wt_g00, nullptr,nullptr, B1,128, N,128,0);
  k_mgemm<128,us16><<<GB,256,0,stream>>>(B0,B0,128, wt_g10, nullptr,nullptr, B2,128, N,128,0);
  // ---- block 0 ----
  k_agg<<<AB,256,0,stream>>>(B1,csr,rp,cnt,0,dis0,
                             g0_b,g0_g,g0_be,g0_rm,g0_rv, nullptr, B0,1,N);      // h0 -> B0
  k_mgemm<128,us16><<<GB,256,0,stream>>>(B0,B0,128, wt_g01, nullptr,nullptr, B1,128, N,128,0);
  k_agg<<<AB,256,0,stream>>>(B1,csr,rp,cnt,0,dis0,
                             g0_b+128,g0_g+128,g0_be+128,g0_rm+128,g0_rv+128, B0, B3,0,N); // x0 -> B3
  // ---- block 1 ----
  k_agg<<<AB,256,0,stream>>>(B2,csr,rp,cnt,N,dis1,
                             g1_b,g1_g,g1_be,g1_rm,g1_rv, nullptr, B0,1,N);      // h1 -> B0
  k_mgemm<128,us16><<<GB,256,0,stream>>>(B0,B0,128, wt_g11, nullptr,nullptr, B1,128, N,128,0);
  k_agg<<<AB,256,0,stream>>>(B1,csr,rp,cnt,N,dis1,
                             g1_b+128,g1_g+128,g1_be+128,g1_rm+128,g1_rv+128, B0, B2,0,N); // x1 -> B2
  // ---- predictor ----
  k_const64<<<1,64,0,stream>>>(B3,B2,seed,p_w1,p_b1,c64);
  k_mgemm<64,us16><<<GB,256,0,stream>>>(B3,B2,128, wt_p1, nullptr, c64, Z1,64, N,256,1);
  k_mgemm<64,us16><<<GB,256,0,stream>>>(Z1,Z1,64,  wt_p2, p_b2, nullptr, Z2,64, N,64,1);
  k_outdot<<<(N+255)/256,256,0,stream>>>(Z2,p_w3,p_b3,out,N);
}